// Round 5
// baseline (632.902 us; speedup 1.0000x reference)
//
#include <hip/hip_runtime.h>
#include <math.h>

#define DIMC 384
#define NHD  6
#define HD   64
#define WSZ  14
#define NTOK 196
#define NWIN 200
#define NWH  1200
#define MWIN 39200
#define MX   32768
#define MLPD 1536

typedef short short8 __attribute__((ext_vector_type(8)));
typedef float f32x4 __attribute__((ext_vector_type(4)));

__device__ __forceinline__ unsigned short f2bf(float f) {
  unsigned int u = __float_as_uint(f);
  u = (u + 0x7fffu + ((u >> 16) & 1u)) >> 16;
  return (unsigned short)u;
}
__device__ __forceinline__ unsigned int pkbf(float a, float b) {
  unsigned int r; asm("v_cvt_pk_bf16_f32 %0, %1, %2" : "=v"(r) : "v"(a), "v"(b)); return r;
}

typedef const __attribute__((address_space(1))) unsigned int* gptr_t;
typedef __attribute__((address_space(3))) unsigned int* lptr_t;
__device__ __forceinline__ void gload16(const unsigned short* g, unsigned short* l) {
  __builtin_amdgcn_global_load_lds((gptr_t)(const void*)g, (lptr_t)(void*)l, 16, 0, 0);
}

// ---------- weight transpose + bf16 convert: out[n*K+k] = bf16(in[k*N+n]) ----------
__global__ void wtrans_kernel(const float* __restrict__ in, unsigned short* __restrict__ out,
                              int K, int N) {
  int id = blockIdx.x * 256 + threadIdx.x;
  if (id >= K * N) return;
  int n = id / K, k = id - n * K;
  out[id] = f2bf(in[(size_t)k * N + n]);
}

// ---------- relcat: [64][64] bf16, rows 0..26 = relh, 27..53 = relw, rest 0 ----------
__global__ void relprep_kernel(const float* __restrict__ relh, const float* __restrict__ relw,
                               unsigned short* __restrict__ relcat) {
  int id = blockIdx.x * 256 + threadIdx.x;
  if (id >= 64 * 64) return;
  int rc = id >> 6, d = id & 63;
  float v = 0.f;
  if (rc < 27) v = relh[rc * 64 + d];
  else if (rc < 54) v = relw[(rc - 27) * 64 + d];
  relcat[id] = f2bf(v);
}

// ---------- zero vT pad columns 196..207 ----------
__global__ void vpad_kernel(unsigned short* __restrict__ vT) {
  int id = blockIdx.x * 256 + threadIdx.x;
  if (id >= 76800 * 3) return;
  int row = id / 3, part = id - row * 3;
  *(int2*)(vT + (size_t)row * 208 + 196 + part * 4) = make_int2(0, 0);
}

// ---------- LN1 + window partition -> bf16 windowed tokens ----------
__global__ __launch_bounds__(64) void ln1win_kernel(const float* __restrict__ x,
    const float* __restrict__ w, const float* __restrict__ b, unsigned short* __restrict__ xw) {
  int t = blockIdx.x;
  int lane = threadIdx.x;
  int win = t / NTOK, p = t - win * NTOK;
  int bb = win / 25, rem = win - bb * 25;
  int wi = rem / 5, wj = rem - wi * 5;
  int i = p / WSZ, j = p - i * WSZ;
  int r = wi * WSZ + i, c = wj * WSZ + j;
  unsigned short* o = xw + (size_t)t * DIMC;
  if (r >= 64 || c >= 64) {
    #pragma unroll
    for (int q = 0; q < 6; q++) o[lane + q * 64] = 0;
    return;
  }
  const float* xr = x + (((size_t)bb * 64 + r) * 64 + c) * DIMC;
  float v[6]; float s = 0.f, s2 = 0.f;
  #pragma unroll
  for (int q = 0; q < 6; q++) { float f = xr[lane + q * 64]; v[q] = f; s += f; s2 += f * f; }
  #pragma unroll
  for (int off = 32; off; off >>= 1) { s += __shfl_xor(s, off); s2 += __shfl_xor(s2, off); }
  float mean = s * (1.f / DIMC);
  float var  = s2 * (1.f / DIMC) - mean * mean;
  float rstd = rsqrtf(var + 1e-5f);
  #pragma unroll
  for (int q = 0; q < 6; q++) {
    int d = lane + q * 64;
    o[d] = f2bf((v[q] - mean) * rstd * w[d] + b[d]);
  }
}

// ---------- LN2 ----------
__global__ __launch_bounds__(64) void ln2_kernel(const float* __restrict__ x2,
    const float* __restrict__ w, const float* __restrict__ b, unsigned short* __restrict__ h2) {
  int t = blockIdx.x; int lane = threadIdx.x;
  const float* xr = x2 + (size_t)t * DIMC;
  unsigned short* o = h2 + (size_t)t * DIMC;
  float v[6]; float s = 0.f, s2 = 0.f;
  #pragma unroll
  for (int q = 0; q < 6; q++) { float f = xr[lane + q * 64]; v[q] = f; s += f; s2 += f * f; }
  #pragma unroll
  for (int off = 32; off; off >>= 1) { s += __shfl_xor(s, off); s2 += __shfl_xor(s2, off); }
  float mean = s * (1.f / DIMC);
  float var  = s2 * (1.f / DIMC) - mean * mean;
  float rstd = rsqrtf(var + 1e-5f);
  #pragma unroll
  for (int q = 0; q < 6; q++) {
    int d = lane + q * 64;
    o[d] = f2bf((v[q] - mean) * rstd * w[d] + b[d]);
  }
}

// ---------- m97-structure bf16 MFMA GEMM, SWAPPED operands ----------
template <int EPI>
__global__ __launch_bounds__(256) void gemm_kernel(
    const unsigned short* __restrict__ A, const unsigned short* __restrict__ WT,
    int Mrows, int Kd,
    const float* __restrict__ bias, const float* __restrict__ addin,
    float* __restrict__ outf, unsigned short* __restrict__ outb,
    unsigned short* __restrict__ outb2) {
  __shared__ unsigned short As[128 * 32];
  __shared__ unsigned short Bs[128 * 32];
  const int row0 = blockIdx.x * 128, col0 = blockIdx.y * 128;
  const int tid = threadIdx.x;
  const int l = tid & 63, wid = tid >> 6;
  const int fr = l & 15, fk = (l >> 4) * 8;
  const int wr = (wid >> 1) * 64, wc = (wid & 1) * 64;
  const int sr = l >> 2, sc = (l & 3) * 8;
  f32x4 acc[4][4] = {};
  const unsigned short* ap = A + (size_t)row0 * Kd;
  const unsigned short* bp = WT + (size_t)col0 * Kd;
  for (int k0 = 0; k0 < Kd; k0 += 32) {
    #pragma unroll
    for (int j = 0; j < 2; j++) {
      int chunk = j * 4 + wid;
      gload16(ap + (size_t)(chunk * 16 + sr) * Kd + k0 + sc, &As[chunk * 512]);
      gload16(bp + (size_t)(chunk * 16 + sr) * Kd + k0 + sc, &Bs[chunk * 512]);
    }
    __syncthreads();
    short8 a[4], b[4];
    #pragma unroll
    for (int fi = 0; fi < 4; fi++) {
      a[fi] = *(const short8*)&As[(wr + fi * 16 + fr) * 32 + fk];
      b[fi] = *(const short8*)&Bs[(wc + fi * 16 + fr) * 32 + fk];
    }
    #pragma unroll
    for (int fi = 0; fi < 4; fi++)
      #pragma unroll
      for (int fj = 0; fj < 4; fj++)
        acc[fi][fj] = __builtin_amdgcn_mfma_f32_16x16x32_bf16(b[fj], a[fi], acc[fi][fj], 0, 0, 0);
    __syncthreads();
  }
  #pragma unroll
  for (int fi = 0; fi < 4; fi++) {
    const int gr = row0 + wr + fi * 16 + fr;
    if (gr >= Mrows) continue;
    int wv_ = 0, p = 0, valid = 1; size_t pixbase = 0;
    if (EPI == 0 || EPI == 1) { wv_ = gr / NTOK; p = gr - wv_ * NTOK; }
    if (EPI == 1) {
      int bb = wv_ / 25, rem2 = wv_ - bb * 25;
      int wi = rem2 / 5, wj = rem2 - wi * 5;
      int i = p / WSZ, j = p - i * WSZ;
      int rr = wi * WSZ + i, cc = wj * WSZ + j;
      valid = (rr < 64) && (cc < 64);
      pixbase = (((size_t)bb * 64 + rr) * 64 + cc) * DIMC;
    }
    #pragma unroll
    for (int fj = 0; fj < 4; fj++) {
      const int gcb = col0 + wc + fj * 16 + (l >> 4) * 4;
      f32x4 v = acc[fi][fj];
      float4 bv = *(const float4*)&bias[gcb];
      float t0 = v[0] + bv.x, t1 = v[1] + bv.y, t2 = v[2] + bv.z, t3 = v[3] + bv.w;
      if (EPI == 0) {
        int s = gcb / 384, rem = gcb - s * 384;
        int hh = rem >> 6, d0 = gcb & 63;
        int whh = wv_ * NHD + hh;
        if (s < 2) {
          *(int2*)&outb[((size_t)s * NWH + whh) * (NTOK * 64) + p * 64 + d0] =
              make_int2((int)pkbf(t0, t1), (int)pkbf(t2, t3));
        } else {
          unsigned short* vb = outb2 + ((size_t)whh * 64 + d0) * 208 + p;
          vb[0] = f2bf(t0); vb[208] = f2bf(t1); vb[416] = f2bf(t2); vb[624] = f2bf(t3);
        }
      } else if (EPI == 1) {
        if (valid) {
          size_t idx = pixbase + gcb;
          float4 ad = *(const float4*)&addin[idx];
          float4 o = make_float4(t0 + ad.x, t1 + ad.y, t2 + ad.z, t3 + ad.w);
          *(float4*)&outf[idx] = o;
        }
      } else if (EPI == 2) {
        float g0 = 0.5f * t0 * (1.f + erff(t0 * 0.70710678118654752f));
        float g1 = 0.5f * t1 * (1.f + erff(t1 * 0.70710678118654752f));
        float g2 = 0.5f * t2 * (1.f + erff(t2 * 0.70710678118654752f));
        float g3 = 0.5f * t3 * (1.f + erff(t3 * 0.70710678118654752f));
        *(int2*)&outb[(size_t)gr * MLPD + gcb] =
            make_int2((int)pkbf(g0, g1), (int)pkbf(g2, g3));
      } else {
        size_t idx = (size_t)gr * DIMC + gcb;
        float4 ad = *(const float4*)&addin[idx];
        float4 o = make_float4(t0 + ad.x, t1 + ad.y, t2 + ad.z, t3 + ad.w);
        *(float4*)&outf[idx] = o;
      }
    }
  }
}

// ---------- MFMA attention: VT in LDS, P/RELB union per wave, 3 blocks/CU ----------
__global__ __launch_bounds__(256, 3) void attn_mfma_kernel(
    const unsigned short* __restrict__ qk_g,   // [2][1200][196][64] bf16
    const unsigned short* __restrict__ vT_g,   // [1200][64][208] bf16 (cols 196..207 zeroed)
    const unsigned short* __restrict__ relcat, // [64][64] bf16
    unsigned short* __restrict__ attnout) {    // [200*196][384] bf16
  __shared__ __align__(16) unsigned short VT[64 * 216];  // cols 196..215 zero; 2-way banks
  __shared__ __align__(16) char SW[4][6656];             // per-wave: P bf16[16][208] U RELB f32[16][68]
  const int wh = blockIdx.x, y = blockIdx.y;
  const int w = wh / NHD, h = wh - w * NHD;
  const int tid = threadIdx.x;
  // stage V^T: 64 rows x 27 int4-chunks (chunk 26 = zeros for cols 208..215)
  const unsigned short* vrow = vT_g + (size_t)wh * 64 * 208;
  for (int e = tid; e < 64 * 27; e += 256) {
    int d = e / 27, c = e - d * 27;
    int4 val = {0, 0, 0, 0};
    if (c < 26) val = *(const int4*)(vrow + d * 208 + c * 8);
    *(int4*)&VT[d * 216 + c * 8] = val;
  }
  __syncthreads();
  const int l15 = tid & 15, g = (tid >> 4) & 3, wv = tid >> 6;
  unsigned short* P = (unsigned short*)&SW[wv][0];       // [16][208]
  float* RELB = (float*)&SW[wv][0];                      // [16][68]
  const unsigned short* qg = qk_g + (size_t)wh * (NTOK * 64);
  const unsigned short* kg = qk_g + (size_t)(NWH + wh) * (NTOK * 64);
  const int tbeg = y * 7, tend = y ? 13 : 7;
  for (int tile = tbeg + wv; tile < tend; tile += 4) {
    const int row0 = tile * 16;
    short8 qf[2];
    #pragma unroll
    for (int kk = 0; kk < 2; kk++)
      qf[kk] = *(const short8*)(qg + (size_t)(row0 + l15) * 64 + kk * 32 + g * 8);
    // REL = relcat . Q^T -> RELB[q][relrow]
    f32x4 ar[4] = {};
    #pragma unroll
    for (int t = 0; t < 4; t++)
      #pragma unroll
      for (int kk = 0; kk < 2; kk++) {
        short8 af = *(const short8*)(relcat + (t * 16 + l15) * 64 + kk * 32 + g * 8);
        ar[t] = __builtin_amdgcn_mfma_f32_16x16x32_bf16(af, qf[kk], ar[t], 0, 0, 0);
      }
    #pragma unroll
    for (int t = 0; t < 4; t++)
      *(f32x4*)&RELB[l15 * 68 + t * 16 + g * 4] = ar[t];
    __builtin_amdgcn_wave_barrier();
    // S^T = K . Q^T : lane holds q=l15, keys 16kt+4g+r
    f32x4 as_[13] = {};
    #pragma unroll
    for (int kt = 0; kt < 13; kt++)
      #pragma unroll
      for (int kk = 0; kk < 2; kk++) {
        short8 kf = *(const short8*)(kg + (size_t)(kt * 16 + l15) * 64 + kk * 32 + g * 8);
        as_[kt] = __builtin_amdgcn_mfma_f32_16x16x32_bf16(kf, qf[kk], as_[kt], 0, 0, 0);
      }
    // softmax
    int tok = row0 + l15; int tq = tok < 196 ? tok : 195;
    int qi = tq / 14, qj = tq - qi * 14;
    const float* rbh = &RELB[l15 * 68 + qi + 13];
    const float* rbw = &RELB[l15 * 68 + 27 + qj + 13];
    float m = -1e30f;
    #pragma unroll
    for (int kt = 0; kt < 13; kt++)
      #pragma unroll
      for (int r = 0; r < 4; r++) {
        int key = kt * 16 + g * 4 + r;
        int ki = key / 14, kj = key - ki * 14;
        float s = as_[kt][r] * 0.125f + rbh[-ki] + rbw[-kj];
        if (kt == 12) s = (g == 0) ? s : -1e30f;   // keys >= 196 masked -> exact zeros in P
        as_[kt][r] = s; m = fmaxf(m, s);
      }
    m = fmaxf(m, __shfl_xor(m, 16)); m = fmaxf(m, __shfl_xor(m, 32));
    float sum = 0.f;
    #pragma unroll
    for (int kt = 0; kt < 13; kt++)
      #pragma unroll
      for (int r = 0; r < 4; r++) {
        float p = __expf(as_[kt][r] - m);
        as_[kt][r] = p; sum += p;
      }
    sum += __shfl_xor(sum, 16); sum += __shfl_xor(sum, 32);
    float inv = 1.f / sum;
    #pragma unroll
    for (int kt = 0; kt < 13; kt++) {
      *(int2*)&P[l15 * 208 + kt * 16 + g * 4] =
          make_int2((int)pkbf(as_[kt][0] * inv, as_[kt][1] * inv),
                    (int)pkbf(as_[kt][2] * inv, as_[kt][3] * inv));
    }
    __builtin_amdgcn_wave_barrier();
    // O = P . V : clamped fragment reads (mismatches hit all-zero operands)
    f32x4 ao[4] = {};
    #pragma unroll
    for (int kk = 0; kk < 7; kk++) {
      int ko = kk * 32 + g * 8;
      int kop = ko > 192 ? 192 : ko;
      int kov = ko > 196 ? 196 : ko;
      short8 pa = *(const short8*)&P[l15 * 208 + kop];
      #pragma unroll
      for (int dt = 0; dt < 4; dt++) {
        short8 vb = *(const short8*)&VT[(dt * 16 + l15) * 216 + kov];
        ao[dt] = __builtin_amdgcn_mfma_f32_16x16x32_bf16(pa, vb, ao[dt], 0, 0, 0);
      }
    }
    #pragma unroll
    for (int dt = 0; dt < 4; dt++)
      #pragma unroll
      for (int r = 0; r < 4; r++) {
        int tk = row0 + g * 4 + r;
        if (tk < 196)
          attnout[((size_t)w * NTOK + tk) * DIMC + h * 64 + dt * 16 + l15] = f2bf(ao[dt][r]);
      }
    __builtin_amdgcn_wave_barrier();
  }
}

extern "C" void kernel_launch(void* const* d_in, const int* in_sizes, int n_in,
                              void* d_out, int out_size, void* d_ws, size_t ws_size,
                              hipStream_t stream) {
  const float* x     = (const float*)d_in[0];
  const float* ln1w  = (const float*)d_in[1];
  const float* ln1b  = (const float*)d_in[2];
  const float* qkvw  = (const float*)d_in[3];
  const float* qkvb  = (const float*)d_in[4];
  const float* projw = (const float*)d_in[5];
  const float* projb = (const float*)d_in[6];
  const float* relh  = (const float*)d_in[7];
  const float* relw  = (const float*)d_in[8];
  const float* ln2w  = (const float*)d_in[9];
  const float* ln2b  = (const float*)d_in[10];
  const float* fc1w  = (const float*)d_in[11];
  const float* fc1b  = (const float*)d_in[12];
  const float* fc2w  = (const float*)d_in[13];
  const float* fc2b  = (const float*)d_in[14];

  const size_t R0 = 0;
  const size_t R1 = R0 + 50331648;
  const size_t R2 = R1 + 100663296;
  const size_t R3 = R2 + 30105600;
  const size_t NEED = R3 + 3547136;
  if (ws_size < NEED) return;
  char* ws = (char*)d_ws;
  unsigned short* xw     = (unsigned short*)(ws + R0);
  float*          x2     = (float*)(ws + R0);
  unsigned short* qk_g   = (unsigned short*)(ws + R1);
  unsigned short* vT_g   = qk_g + (size_t)2 * NWH * NTOK * 64;
  unsigned short* hidden = (unsigned short*)(ws + R1);
  unsigned short* attno  = (unsigned short*)(ws + R2);
  unsigned short* h2     = (unsigned short*)(ws + R2);
  unsigned short* qkvwT  = (unsigned short*)(ws + R3);
  unsigned short* projwT = qkvwT + 442368;
  unsigned short* fc1wT  = projwT + 147456;
  unsigned short* fc2wT  = fc1wT + 589824;
  unsigned short* relcat = fc2wT + 589824;

  wtrans_kernel<<<1728, 256, 0, stream>>>(qkvw, qkvwT, 384, 1152);
  wtrans_kernel<<<576, 256, 0, stream>>>(projw, projwT, 384, 384);
  wtrans_kernel<<<2304, 256, 0, stream>>>(fc1w, fc1wT, 384, 1536);
  wtrans_kernel<<<2304, 256, 0, stream>>>(fc2w, fc2wT, 1536, 384);
  relprep_kernel<<<16, 256, 0, stream>>>(relh, relw, relcat);
  vpad_kernel<<<900, 256, 0, stream>>>(vT_g);
  ln1win_kernel<<<MWIN, 64, 0, stream>>>(x, ln1w, ln1b, xw);
  gemm_kernel<0><<<dim3(307, 9), 256, 0, stream>>>(xw, qkvwT, MWIN, 384, qkvb, nullptr, nullptr, qk_g, vT_g);
  attn_mfma_kernel<<<dim3(NWH, 2), 256, 0, stream>>>(qk_g, vT_g, relcat, attno);
  gemm_kernel<1><<<dim3(307, 3), 256, 0, stream>>>(attno, projwT, MWIN, 384, projb, x, x2, nullptr, nullptr);
  ln2_kernel<<<MX, 64, 0, stream>>>(x2, ln2w, ln2b, h2);
  gemm_kernel<2><<<dim3(256, 12), 256, 0, stream>>>(h2, fc1wT, MX, 384, fc1b, nullptr, nullptr, hidden, nullptr);
  gemm_kernel<3><<<dim3(256, 3), 256, 0, stream>>>(hidden, fc2wT, MX, 1536, fc2b, x2, (float*)d_out, nullptr, nullptr);
}

// Round 6
// 449.815 us; speedup vs baseline: 1.4070x; 1.4070x over previous
//
#include <hip/hip_runtime.h>
#include <math.h>

#define DIMC 384
#define NHD  6
#define HD   64
#define WSZ  14
#define NTOK 196
#define NWIN 200
#define NWH  1200
#define MWIN 39200
#define MX   32768
#define MLPD 1536

typedef short short8 __attribute__((ext_vector_type(8)));
typedef float f32x4 __attribute__((ext_vector_type(4)));

__device__ __forceinline__ unsigned short f2bf(float f) {
  unsigned int u = __float_as_uint(f);
  u = (u + 0x7fffu + ((u >> 16) & 1u)) >> 16;
  return (unsigned short)u;
}
__device__ __forceinline__ unsigned int pkbf(float a, float b) {
  unsigned int r; asm("v_cvt_pk_bf16_f32 %0, %1, %2" : "=v"(r) : "v"(a), "v"(b)); return r;
}

typedef const __attribute__((address_space(1))) unsigned int* gptr_t;
typedef __attribute__((address_space(3))) unsigned int* lptr_t;
__device__ __forceinline__ void gload16(const unsigned short* g, unsigned short* l) {
  __builtin_amdgcn_global_load_lds((gptr_t)(const void*)g, (lptr_t)(void*)l, 16, 0, 0);
}

// ---------- weight transpose + bf16 convert: out[n*K+k] = bf16(in[k*N+n]) ----------
__global__ void wtrans_kernel(const float* __restrict__ in, unsigned short* __restrict__ out,
                              int K, int N) {
  int id = blockIdx.x * 256 + threadIdx.x;
  if (id >= K * N) return;
  int n = id / K, k = id - n * K;
  out[id] = f2bf(in[(size_t)k * N + n]);
}

// ---------- relcat x8: [64][64] bf16, rows 0..26 = 8*relh, 27..53 = 8*relw, rest 0 ----------
// (x8 compensates q being pre-scaled by 1/8; both scalings are powers of 2 -> exact)
__global__ void relprep_kernel(const float* __restrict__ relh, const float* __restrict__ relw,
                               unsigned short* __restrict__ relcat) {
  int id = blockIdx.x * 256 + threadIdx.x;
  if (id >= 64 * 64) return;
  int rc = id >> 6, d = id & 63;
  float v = 0.f;
  if (rc < 27) v = relh[rc * 64 + d] * 8.f;
  else if (rc < 54) v = relw[(rc - 27) * 64 + d] * 8.f;
  relcat[id] = f2bf(v);
}

// ---------- zero vT pad columns 196..207 ----------
__global__ void vpad_kernel(unsigned short* __restrict__ vT) {
  int id = blockIdx.x * 256 + threadIdx.x;
  if (id >= 76800 * 3) return;
  int row = id / 3, part = id - row * 3;
  *(int2*)(vT + (size_t)row * 208 + 196 + part * 4) = make_int2(0, 0);
}

// ---------- LN1 + window partition -> bf16 windowed tokens ----------
__global__ __launch_bounds__(64) void ln1win_kernel(const float* __restrict__ x,
    const float* __restrict__ w, const float* __restrict__ b, unsigned short* __restrict__ xw) {
  int t = blockIdx.x;
  int lane = threadIdx.x;
  int win = t / NTOK, p = t - win * NTOK;
  int bb = win / 25, rem = win - bb * 25;
  int wi = rem / 5, wj = rem - wi * 5;
  int i = p / WSZ, j = p - i * WSZ;
  int r = wi * WSZ + i, c = wj * WSZ + j;
  unsigned short* o = xw + (size_t)t * DIMC;
  if (r >= 64 || c >= 64) {
    #pragma unroll
    for (int q = 0; q < 6; q++) o[lane + q * 64] = 0;
    return;
  }
  const float* xr = x + (((size_t)bb * 64 + r) * 64 + c) * DIMC;
  float v[6]; float s = 0.f, s2 = 0.f;
  #pragma unroll
  for (int q = 0; q < 6; q++) { float f = xr[lane + q * 64]; v[q] = f; s += f; s2 += f * f; }
  #pragma unroll
  for (int off = 32; off; off >>= 1) { s += __shfl_xor(s, off); s2 += __shfl_xor(s2, off); }
  float mean = s * (1.f / DIMC);
  float var  = s2 * (1.f / DIMC) - mean * mean;
  float rstd = rsqrtf(var + 1e-5f);
  #pragma unroll
  for (int q = 0; q < 6; q++) {
    int d = lane + q * 64;
    o[d] = f2bf((v[q] - mean) * rstd * w[d] + b[d]);
  }
}

// ---------- LN2 ----------
__global__ __launch_bounds__(64) void ln2_kernel(const float* __restrict__ x2,
    const float* __restrict__ w, const float* __restrict__ b, unsigned short* __restrict__ h2) {
  int t = blockIdx.x; int lane = threadIdx.x;
  const float* xr = x2 + (size_t)t * DIMC;
  unsigned short* o = h2 + (size_t)t * DIMC;
  float v[6]; float s = 0.f, s2 = 0.f;
  #pragma unroll
  for (int q = 0; q < 6; q++) { float f = xr[lane + q * 64]; v[q] = f; s += f; s2 += f * f; }
  #pragma unroll
  for (int off = 32; off; off >>= 1) { s += __shfl_xor(s, off); s2 += __shfl_xor(s2, off); }
  float mean = s * (1.f / DIMC);
  float var  = s2 * (1.f / DIMC) - mean * mean;
  float rstd = rsqrtf(var + 1e-5f);
  #pragma unroll
  for (int q = 0; q < 6; q++) {
    int d = lane + q * 64;
    o[d] = f2bf((v[q] - mean) * rstd * w[d] + b[d]);
  }
}

// ---------- m97-structure bf16 MFMA GEMM, SWAPPED operands ----------
template <int EPI>
__global__ __launch_bounds__(256) void gemm_kernel(
    const unsigned short* __restrict__ A, const unsigned short* __restrict__ WT,
    int Mrows, int Kd,
    const float* __restrict__ bias, const float* __restrict__ addin,
    float* __restrict__ outf, unsigned short* __restrict__ outb,
    unsigned short* __restrict__ outb2) {
  __shared__ unsigned short As[128 * 32];
  __shared__ unsigned short Bs[128 * 32];
  const int row0 = blockIdx.x * 128, col0 = blockIdx.y * 128;
  const int tid = threadIdx.x;
  const int l = tid & 63, wid = tid >> 6;
  const int fr = l & 15, fk = (l >> 4) * 8;
  const int wr = (wid >> 1) * 64, wc = (wid & 1) * 64;
  const int sr = l >> 2, sc = (l & 3) * 8;
  f32x4 acc[4][4] = {};
  const unsigned short* ap = A + (size_t)row0 * Kd;
  const unsigned short* bp = WT + (size_t)col0 * Kd;
  for (int k0 = 0; k0 < Kd; k0 += 32) {
    #pragma unroll
    for (int j = 0; j < 2; j++) {
      int chunk = j * 4 + wid;
      gload16(ap + (size_t)(chunk * 16 + sr) * Kd + k0 + sc, &As[chunk * 512]);
      gload16(bp + (size_t)(chunk * 16 + sr) * Kd + k0 + sc, &Bs[chunk * 512]);
    }
    __syncthreads();
    short8 a[4], b[4];
    #pragma unroll
    for (int fi = 0; fi < 4; fi++) {
      a[fi] = *(const short8*)&As[(wr + fi * 16 + fr) * 32 + fk];
      b[fi] = *(const short8*)&Bs[(wc + fi * 16 + fr) * 32 + fk];
    }
    #pragma unroll
    for (int fi = 0; fi < 4; fi++)
      #pragma unroll
      for (int fj = 0; fj < 4; fj++)
        acc[fi][fj] = __builtin_amdgcn_mfma_f32_16x16x32_bf16(b[fj], a[fi], acc[fi][fj], 0, 0, 0);
    __syncthreads();
  }
  #pragma unroll
  for (int fi = 0; fi < 4; fi++) {
    const int gr = row0 + wr + fi * 16 + fr;
    if (gr >= Mrows) continue;
    int wv_ = 0, p = 0, valid = 1; size_t pixbase = 0;
    if (EPI == 0 || EPI == 1) { wv_ = gr / NTOK; p = gr - wv_ * NTOK; }
    if (EPI == 1) {
      int bb = wv_ / 25, rem2 = wv_ - bb * 25;
      int wi = rem2 / 5, wj = rem2 - wi * 5;
      int i = p / WSZ, j = p - i * WSZ;
      int rr = wi * WSZ + i, cc = wj * WSZ + j;
      valid = (rr < 64) && (cc < 64);
      pixbase = (((size_t)bb * 64 + rr) * 64 + cc) * DIMC;
    }
    #pragma unroll
    for (int fj = 0; fj < 4; fj++) {
      const int gcb = col0 + wc + fj * 16 + (l >> 4) * 4;
      f32x4 v = acc[fi][fj];
      float4 bv = *(const float4*)&bias[gcb];
      float t0 = v[0] + bv.x, t1 = v[1] + bv.y, t2 = v[2] + bv.z, t3 = v[3] + bv.w;
      if (EPI == 0) {
        int s = gcb / 384, rem = gcb - s * 384;
        int hh = rem >> 6, d0 = gcb & 63;
        int whh = wv_ * NHD + hh;
        if (s == 0) { t0 *= 0.125f; t1 *= 0.125f; t2 *= 0.125f; t3 *= 0.125f; }  // bake SCALE into q
        if (s < 2) {
          *(int2*)&outb[((size_t)s * NWH + whh) * (NTOK * 64) + p * 64 + d0] =
              make_int2((int)pkbf(t0, t1), (int)pkbf(t2, t3));
        } else {
          unsigned short* vb = outb2 + ((size_t)whh * 64 + d0) * 208 + p;
          vb[0] = f2bf(t0); vb[208] = f2bf(t1); vb[416] = f2bf(t2); vb[624] = f2bf(t3);
        }
      } else if (EPI == 1) {
        if (valid) {
          size_t idx = pixbase + gcb;
          float4 ad = *(const float4*)&addin[idx];
          float4 o = make_float4(t0 + ad.x, t1 + ad.y, t2 + ad.z, t3 + ad.w);
          *(float4*)&outf[idx] = o;
        }
      } else if (EPI == 2) {
        float g0 = 0.5f * t0 * (1.f + erff(t0 * 0.70710678118654752f));
        float g1 = 0.5f * t1 * (1.f + erff(t1 * 0.70710678118654752f));
        float g2 = 0.5f * t2 * (1.f + erff(t2 * 0.70710678118654752f));
        float g3 = 0.5f * t3 * (1.f + erff(t3 * 0.70710678118654752f));
        *(int2*)&outb[(size_t)gr * MLPD + gcb] =
            make_int2((int)pkbf(g0, g1), (int)pkbf(g2, g3));
      } else {
        size_t idx = (size_t)gr * DIMC + gcb;
        float4 ad = *(const float4*)&addin[idx];
        float4 o = make_float4(t0 + ad.x, t1 + ad.y, t2 + ad.z, t3 + ad.w);
        *(float4*)&outf[idx] = o;
      }
    }
  }
}

// ---------- MFMA attention: online-softmax chunks, rel folded into MFMA, 4 blocks/CU ----------
// q pre-scaled 1/8; relcat pre-scaled x8. S = K'.Q'^T over K=96:
//   cols 0..63 = K.Q, 64..77 = onehot(ki).RELh, 78..91 = onehot(kj).RELw, 92..95 = 0
__global__ __launch_bounds__(256) void attn_mfma_kernel(
    const unsigned short* __restrict__ qk_g,   // [2][1200][196][64] bf16
    const unsigned short* __restrict__ vT_g,   // [1200][64][208] bf16 (cols 196..207 zeroed)
    const unsigned short* __restrict__ relcat, // [64][64] bf16 (x8)
    unsigned short* __restrict__ attnout) {    // [200*196][384] bf16
  __shared__ __align__(16) unsigned short VT[64 * 216];  // cols 196..215 zero
  __shared__ __align__(16) unsigned short SW[4][1152];   // per-wave: RELB bf16[16][68] U P bf16[16][40]
  const int wh = blockIdx.x, y = blockIdx.y;
  const int w = wh / NHD, h = wh - w * NHD;
  const int tid = threadIdx.x;
  const unsigned short* vrow = vT_g + (size_t)wh * 64 * 208;
  for (int e = tid; e < 64 * 27; e += 256) {
    int d = e / 27, c = e - d * 27;
    int4 val = {0, 0, 0, 0};
    if (c < 26) val = *(const int4*)(vrow + d * 208 + c * 8);
    *(int4*)&VT[d * 216 + c * 8] = val;
  }
  __syncthreads();
  const int l15 = tid & 15, g = (tid >> 4) & 3, wv = tid >> 6;
  unsigned short* RELB = &SW[wv][0];   // [16][68] bf16
  unsigned short* P    = &SW[wv][0];   // [16][40] bf16 (chunk)
  const unsigned short* qg = qk_g + (size_t)wh * (NTOK * 64);
  const unsigned short* kg = qk_g + (size_t)(NWH + wh) * (NTOK * 64);
  const int tbeg = y * 7, tend = y ? 13 : 7;
  for (int tile = tbeg + wv; tile < tend; tile += 4) {
    const int row0 = tile * 16;
    short8 qf0 = *(const short8*)(qg + (size_t)(row0 + l15) * 64 + g * 8);
    short8 qf1 = *(const short8*)(qg + (size_t)(row0 + l15) * 64 + 32 + g * 8);
    // REL = relcat8 . Q^T  (q pre-scaled 1/8 -> net true rel dots)
    f32x4 ar[4] = {};
    #pragma unroll
    for (int t = 0; t < 4; t++) {
      short8 af0 = *(const short8*)(relcat + (t * 16 + l15) * 64 + g * 8);
      short8 af1 = *(const short8*)(relcat + (t * 16 + l15) * 64 + 32 + g * 8);
      ar[t] = __builtin_amdgcn_mfma_f32_16x16x32_bf16(af0, qf0, ar[t], 0, 0, 0);
      ar[t] = __builtin_amdgcn_mfma_f32_16x16x32_bf16(af1, qf1, ar[t], 0, 0, 0);
    }
    #pragma unroll
    for (int t = 0; t < 4; t++) {
      *(unsigned int*)&RELB[l15 * 68 + t * 16 + g * 4]     = pkbf(ar[t][0], ar[t][1]);
      *(unsigned int*)&RELB[l15 * 68 + t * 16 + g * 4 + 2] = pkbf(ar[t][2], ar[t][3]);
    }
    __builtin_amdgcn_wave_barrier();
    // Q' rel fragment: gather 8 RELB values per lane
    int tok = row0 + l15; int tq = tok < 196 ? tok : 195;
    int qi = tq / 14, qj = tq - qi * 14;
    short8 qf2;
    #pragma unroll
    for (int j = 0; j < 8; j++) {
      int c = g * 8 + j;
      unsigned short vv = 0;
      if (c < 14) vv = RELB[l15 * 68 + (qi - c + 13)];
      else if (c < 28) vv = RELB[l15 * 68 + 27 + (qj - (c - 14) + 13)];
      qf2[j] = (short)vv;
    }
    __builtin_amdgcn_wave_barrier();
    // online flash over 7 chunks of 32 keys
    float m_run = -1e30f, s_run = 0.f;
    f32x4 ao[4] = {};
    #pragma unroll 2
    for (int kk = 0; kk < 7; kk++) {
      f32x4 sc2[2]; float cmax = -1e30f;
      #pragma unroll
      for (int h2 = 0; h2 < 2; h2++) {
        int kt = kk * 2 + h2;
        if (kt < 13) {
          const unsigned short* kr = kg + (size_t)(kt * 16 + l15) * 64 + g * 8;
          short8 kf0 = *(const short8*)(kr);
          short8 kf1 = *(const short8*)(kr + 32);
          int key = kt * 16 + l15;
          int ki = key / 14, kj = key - ki * 14;
          short8 kh;
          #pragma unroll
          for (int j = 0; j < 8; j++) {
            int c = g * 8 + j;
            kh[j] = (short)((c == ki || c == 14 + kj) ? 0x3F80 : 0);
          }
          f32x4 s0 = {};
          s0 = __builtin_amdgcn_mfma_f32_16x16x32_bf16(kf0, qf0, s0, 0, 0, 0);
          s0 = __builtin_amdgcn_mfma_f32_16x16x32_bf16(kf1, qf1, s0, 0, 0, 0);
          s0 = __builtin_amdgcn_mfma_f32_16x16x32_bf16(kh, qf2, s0, 0, 0, 0);
          #pragma unroll
          for (int r = 0; r < 4; r++) {
            float sv = s0[r];
            if (kt == 12 && g != 0) sv = -1e30f;   // keys >= 196 masked
            s0[r] = sv;
            cmax = fmaxf(cmax, sv);
          }
          sc2[h2] = s0;
        } else {
          sc2[h2] = f32x4{-1e30f, -1e30f, -1e30f, -1e30f};
        }
      }
      cmax = fmaxf(cmax, __shfl_xor(cmax, 16));
      cmax = fmaxf(cmax, __shfl_xor(cmax, 32));
      float m_new = fmaxf(m_run, cmax);
      float fac = __expf(m_run - m_new);
      m_run = m_new;
      s_run *= fac;
      #pragma unroll
      for (int r = 0; r < 4; r++) {
        float fr_ = __shfl(fac, g * 4 + r);
        ao[0][r] *= fr_; ao[1][r] *= fr_; ao[2][r] *= fr_; ao[3][r] *= fr_;
      }
      #pragma unroll
      for (int h2 = 0; h2 < 2; h2++) {
        int kt = kk * 2 + h2;
        float p0 = 0.f, p1 = 0.f, p2 = 0.f, p3 = 0.f;
        if (kt < 13) {
          p0 = __expf(sc2[h2][0] - m_new);
          p1 = __expf(sc2[h2][1] - m_new);
          p2 = __expf(sc2[h2][2] - m_new);
          p3 = __expf(sc2[h2][3] - m_new);
          s_run += (p0 + p1) + (p2 + p3);
        }
        *(int2*)&P[l15 * 40 + h2 * 16 + g * 4] =
            make_int2((int)pkbf(p0, p1), (int)pkbf(p2, p3));
      }
      __builtin_amdgcn_wave_barrier();
      short8 pa = *(const short8*)&P[l15 * 40 + g * 8];
      int vcol = kk * 32 + g * 8; if (vcol > 208) vcol = 208;   // zero VT cols pair with zero P
      #pragma unroll
      for (int dt = 0; dt < 4; dt++) {
        short8 vb = *(const short8*)&VT[(dt * 16 + l15) * 216 + vcol];
        ao[dt] = __builtin_amdgcn_mfma_f32_16x16x32_bf16(pa, vb, ao[dt], 0, 0, 0);
      }
      __builtin_amdgcn_wave_barrier();
    }
    // finalize: reduce sum across g, broadcast per-row inv, store
    s_run += __shfl_xor(s_run, 16);
    s_run += __shfl_xor(s_run, 32);
    float inv = 1.f / s_run;
    #pragma unroll
    for (int r = 0; r < 4; r++) {
      float ir = __shfl(inv, g * 4 + r);
      int tk = row0 + g * 4 + r;
      if (tk < 196) {
        #pragma unroll
        for (int dt = 0; dt < 4; dt++)
          attnout[((size_t)w * NTOK + tk) * DIMC + h * 64 + dt * 16 + l15] = f2bf(ao[dt][r] * ir);
      }
    }
  }
}

extern "C" void kernel_launch(void* const* d_in, const int* in_sizes, int n_in,
                              void* d_out, int out_size, void* d_ws, size_t ws_size,
                              hipStream_t stream) {
  const float* x     = (const float*)d_in[0];
  const float* ln1w  = (const float*)d_in[1];
  const float* ln1b  = (const float*)d_in[2];
  const float* qkvw  = (const float*)d_in[3];
  const float* qkvb  = (const float*)d_in[4];
  const float* projw = (const float*)d_in[5];
  const float* projb = (const float*)d_in[6];
  const float* relh  = (const float*)d_in[7];
  const float* relw  = (const float*)d_in[8];
  const float* ln2w  = (const float*)d_in[9];
  const float* ln2b  = (const float*)d_in[10];
  const float* fc1w  = (const float*)d_in[11];
  const float* fc1b  = (const float*)d_in[12];
  const float* fc2w  = (const float*)d_in[13];
  const float* fc2b  = (const float*)d_in[14];

  const size_t R0 = 0;
  const size_t R1 = R0 + 50331648;
  const size_t R2 = R1 + 100663296;
  const size_t R3 = R2 + 30105600;
  const size_t NEED = R3 + 3547136;
  if (ws_size < NEED) return;
  char* ws = (char*)d_ws;
  unsigned short* xw     = (unsigned short*)(ws + R0);
  float*          x2     = (float*)(ws + R0);
  unsigned short* qk_g   = (unsigned short*)(ws + R1);
  unsigned short* vT_g   = qk_g + (size_t)2 * NWH * NTOK * 64;
  unsigned short* hidden = (unsigned short*)(ws + R1);
  unsigned short* attno  = (unsigned short*)(ws + R2);
  unsigned short* h2     = (unsigned short*)(ws + R2);
  unsigned short* qkvwT  = (unsigned short*)(ws + R3);
  unsigned short* projwT = qkvwT + 442368;
  unsigned short* fc1wT  = projwT + 147456;
  unsigned short* fc2wT  = fc1wT + 589824;
  unsigned short* relcat = fc2wT + 589824;

  wtrans_kernel<<<1728, 256, 0, stream>>>(qkvw, qkvwT, 384, 1152);
  wtrans_kernel<<<576, 256, 0, stream>>>(projw, projwT, 384, 384);
  wtrans_kernel<<<2304, 256, 0, stream>>>(fc1w, fc1wT, 384, 1536);
  wtrans_kernel<<<2304, 256, 0, stream>>>(fc2w, fc2wT, 1536, 384);
  relprep_kernel<<<16, 256, 0, stream>>>(relh, relw, relcat);
  vpad_kernel<<<900, 256, 0, stream>>>(vT_g);
  ln1win_kernel<<<MWIN, 64, 0, stream>>>(x, ln1w, ln1b, xw);
  gemm_kernel<0><<<dim3(307, 9), 256, 0, stream>>>(xw, qkvwT, MWIN, 384, qkvb, nullptr, nullptr, qk_g, vT_g);
  attn_mfma_kernel<<<dim3(NWH, 2), 256, 0, stream>>>(qk_g, vT_g, relcat, attno);
  gemm_kernel<1><<<dim3(307, 3), 256, 0, stream>>>(attno, projwT, MWIN, 384, projb, x, x2, nullptr, nullptr);
  ln2_kernel<<<MX, 64, 0, stream>>>(x2, ln2w, ln2b, h2);
  gemm_kernel<2><<<dim3(256, 12), 256, 0, stream>>>(h2, fc1wT, MX, 384, fc1b, nullptr, nullptr, hidden, nullptr);
  gemm_kernel<3><<<dim3(256, 3), 256, 0, stream>>>(hidden, fc2wT, MX, 1536, fc2b, x2, (float*)d_out, nullptr, nullptr);
}

// Round 7
// 389.337 us; speedup vs baseline: 1.6256x; 1.1553x over previous
//
#include <hip/hip_runtime.h>
#include <math.h>

#define DIMC 384
#define NHD  6
#define HD   64
#define WSZ  14
#define NTOK 196
#define NWIN 200
#define NWH  1200
#define MWIN 39200
#define MX   32768
#define MLPD 1536

typedef short short8 __attribute__((ext_vector_type(8)));
typedef float f32x4 __attribute__((ext_vector_type(4)));
typedef float f32x16 __attribute__((ext_vector_type(16)));

__device__ __forceinline__ unsigned short f2bf(float f) {
  unsigned int u = __float_as_uint(f);
  u = (u + 0x7fffu + ((u >> 16) & 1u)) >> 16;
  return (unsigned short)u;
}
__device__ __forceinline__ unsigned int pkbf(float a, float b) {
  unsigned int r; asm("v_cvt_pk_bf16_f32 %0, %1, %2" : "=v"(r) : "v"(a), "v"(b)); return r;
}

typedef const __attribute__((address_space(1))) unsigned int* gptr_t;
typedef __attribute__((address_space(3))) unsigned int* lptr_t;
__device__ __forceinline__ void gload16(const unsigned short* g, unsigned short* l) {
  __builtin_amdgcn_global_load_lds((gptr_t)(const void*)g, (lptr_t)(void*)l, 16, 0, 0);
}

// ---------- weight transpose + bf16 convert ----------
__global__ void wtrans_kernel(const float* __restrict__ in, unsigned short* __restrict__ out,
                              int K, int N) {
  int id = blockIdx.x * 256 + threadIdx.x;
  if (id >= K * N) return;
  int n = id / K, k = id - n * K;
  out[id] = f2bf(in[(size_t)k * N + n]);
}

// ---------- relcat x8: rows 0..26 = 8*relh, 27..53 = 8*relw, rest 0 ----------
__global__ void relprep_kernel(const float* __restrict__ relh, const float* __restrict__ relw,
                               unsigned short* __restrict__ relcat) {
  int id = blockIdx.x * 256 + threadIdx.x;
  if (id >= 64 * 64) return;
  int rc = id >> 6, d = id & 63;
  float v = 0.f;
  if (rc < 27) v = relh[rc * 64 + d] * 8.f;
  else if (rc < 54) v = relw[(rc - 27) * 64 + d] * 8.f;
  relcat[id] = f2bf(v);
}

// ---------- zero vT pad columns 196..207 ----------
__global__ void vpad_kernel(unsigned short* __restrict__ vT) {
  int id = blockIdx.x * 256 + threadIdx.x;
  if (id >= 76800 * 3) return;
  int row = id / 3, part = id - row * 3;
  *(int2*)(vT + (size_t)row * 208 + 196 + part * 4) = make_int2(0, 0);
}

// ---------- LN1 + window partition ----------
__global__ __launch_bounds__(64) void ln1win_kernel(const float* __restrict__ x,
    const float* __restrict__ w, const float* __restrict__ b, unsigned short* __restrict__ xw) {
  int t = blockIdx.x;
  int lane = threadIdx.x;
  int win = t / NTOK, p = t - win * NTOK;
  int bb = win / 25, rem = win - bb * 25;
  int wi = rem / 5, wj = rem - wi * 5;
  int i = p / WSZ, j = p - i * WSZ;
  int r = wi * WSZ + i, c = wj * WSZ + j;
  unsigned short* o = xw + (size_t)t * DIMC;
  if (r >= 64 || c >= 64) {
    #pragma unroll
    for (int q = 0; q < 6; q++) o[lane + q * 64] = 0;
    return;
  }
  const float* xr = x + (((size_t)bb * 64 + r) * 64 + c) * DIMC;
  float v[6]; float s = 0.f, s2 = 0.f;
  #pragma unroll
  for (int q = 0; q < 6; q++) { float f = xr[lane + q * 64]; v[q] = f; s += f; s2 += f * f; }
  #pragma unroll
  for (int off = 32; off; off >>= 1) { s += __shfl_xor(s, off); s2 += __shfl_xor(s2, off); }
  float mean = s * (1.f / DIMC);
  float var  = s2 * (1.f / DIMC) - mean * mean;
  float rstd = rsqrtf(var + 1e-5f);
  #pragma unroll
  for (int q = 0; q < 6; q++) {
    int d = lane + q * 64;
    o[d] = f2bf((v[q] - mean) * rstd * w[d] + b[d]);
  }
}

// ---------- LN2 ----------
__global__ __launch_bounds__(64) void ln2_kernel(const float* __restrict__ x2,
    const float* __restrict__ w, const float* __restrict__ b, unsigned short* __restrict__ h2) {
  int t = blockIdx.x; int lane = threadIdx.x;
  const float* xr = x2 + (size_t)t * DIMC;
  unsigned short* o = h2 + (size_t)t * DIMC;
  float v[6]; float s = 0.f, s2 = 0.f;
  #pragma unroll
  for (int q = 0; q < 6; q++) { float f = xr[lane + q * 64]; v[q] = f; s += f; s2 += f * f; }
  #pragma unroll
  for (int off = 32; off; off >>= 1) { s += __shfl_xor(s, off); s2 += __shfl_xor(s2, off); }
  float mean = s * (1.f / DIMC);
  float var  = s2 * (1.f / DIMC) - mean * mean;
  float rstd = rsqrtf(var + 1e-5f);
  #pragma unroll
  for (int q = 0; q < 6; q++) {
    int d = lane + q * 64;
    o[d] = f2bf((v[q] - mean) * rstd * w[d] + b[d]);
  }
}

// ---------- m97-structure bf16 MFMA GEMM, swapped operands, LDS XOR-swizzle, XCD remap ----------
template <int EPI>
__global__ __launch_bounds__(256) void gemm_kernel(
    const unsigned short* __restrict__ A, const unsigned short* __restrict__ WT,
    int Mrows, int Kd,
    const float* __restrict__ bias, const float* __restrict__ addin,
    float* __restrict__ outf, unsigned short* __restrict__ outb,
    unsigned short* __restrict__ outb2) {
  __shared__ unsigned short As[128 * 32];
  __shared__ unsigned short Bs[128 * 32];
  // XCD-aware bijective remap (m204): consecutive per-XCD ids share the A-panel (bx)
  const int nwg = gridDim.x * gridDim.y;
  const int flat = blockIdx.y * gridDim.x + blockIdx.x;
  const int xcd = flat & 7, q_ = nwg >> 3, r_ = nwg & 7;
  const int wg = (xcd < r_ ? xcd * (q_ + 1) : r_ * (q_ + 1) + (xcd - r_) * q_) + (flat >> 3);
  const int bx = wg / gridDim.y, by = wg - bx * gridDim.y;
  const int row0 = bx * 128, col0 = by * 128;
  const int tid = threadIdx.x;
  const int l = tid & 63, wid = tid >> 6;
  const int fr = l & 15, fk = (l >> 4) * 8;
  const int wr = (wid >> 1) * 64, wc = (wid & 1) * 64;
  const int sr = l >> 2, sc = (l & 3) * 8;
  const int scs = sc ^ (((sr >> 1) & 3) << 3);   // source col swizzle (shorts)
  const int rsw = ((fr >> 1) & 3) << 3;          // read col swizzle
  f32x4 acc[4][4] = {};
  const unsigned short* ap = A + (size_t)row0 * Kd;
  const unsigned short* bp = WT + (size_t)col0 * Kd;
  for (int k0 = 0; k0 < Kd; k0 += 32) {
    #pragma unroll
    for (int j = 0; j < 2; j++) {
      int chunk = j * 4 + wid;
      gload16(ap + (size_t)(chunk * 16 + sr) * Kd + k0 + scs, &As[chunk * 512]);
      gload16(bp + (size_t)(chunk * 16 + sr) * Kd + k0 + scs, &Bs[chunk * 512]);
    }
    __syncthreads();
    short8 a[4], b[4];
    #pragma unroll
    for (int fi = 0; fi < 4; fi++) {
      a[fi] = *(const short8*)&As[(wr + fi * 16 + fr) * 32 + (fk ^ rsw)];
      b[fi] = *(const short8*)&Bs[(wc + fi * 16 + fr) * 32 + (fk ^ rsw)];
    }
    #pragma unroll
    for (int fi = 0; fi < 4; fi++)
      #pragma unroll
      for (int fj = 0; fj < 4; fj++)
        acc[fi][fj] = __builtin_amdgcn_mfma_f32_16x16x32_bf16(b[fj], a[fi], acc[fi][fj], 0, 0, 0);
    __syncthreads();
  }
  #pragma unroll
  for (int fi = 0; fi < 4; fi++) {
    const int gr = row0 + wr + fi * 16 + fr;
    if (gr >= Mrows) continue;
    int wv_ = 0, p = 0, valid = 1; size_t pixbase = 0;
    if (EPI == 0 || EPI == 1) { wv_ = gr / NTOK; p = gr - wv_ * NTOK; }
    if (EPI == 1) {
      int bb = wv_ / 25, rem2 = wv_ - bb * 25;
      int wi = rem2 / 5, wj = rem2 - wi * 5;
      int i = p / WSZ, j = p - i * WSZ;
      int rr = wi * WSZ + i, cc = wj * WSZ + j;
      valid = (rr < 64) && (cc < 64);
      pixbase = (((size_t)bb * 64 + rr) * 64 + cc) * DIMC;
    }
    #pragma unroll
    for (int fj = 0; fj < 4; fj++) {
      const int gcb = col0 + wc + fj * 16 + (l >> 4) * 4;
      f32x4 v = acc[fi][fj];
      float4 bv = *(const float4*)&bias[gcb];
      float t0 = v[0] + bv.x, t1 = v[1] + bv.y, t2 = v[2] + bv.z, t3 = v[3] + bv.w;
      if (EPI == 0) {
        int s = gcb / 384, rem = gcb - s * 384;
        int hh = rem >> 6, d0 = gcb & 63;
        int whh = wv_ * NHD + hh;
        if (s == 0) { t0 *= 0.125f; t1 *= 0.125f; t2 *= 0.125f; t3 *= 0.125f; }
        if (s < 2) {
          *(int2*)&outb[((size_t)s * NWH + whh) * (NTOK * 64) + p * 64 + d0] =
              make_int2((int)pkbf(t0, t1), (int)pkbf(t2, t3));
        } else {
          unsigned short* vb = outb2 + ((size_t)whh * 64 + d0) * 208 + p;
          vb[0] = f2bf(t0); vb[208] = f2bf(t1); vb[416] = f2bf(t2); vb[624] = f2bf(t3);
        }
      } else if (EPI == 1) {
        if (valid) {
          size_t idx = pixbase + gcb;
          float4 ad = *(const float4*)&addin[idx];
          *(float4*)&outf[idx] = make_float4(t0 + ad.x, t1 + ad.y, t2 + ad.z, t3 + ad.w);
        }
      } else if (EPI == 2) {
        float g0 = 0.5f * t0 * (1.f + erff(t0 * 0.70710678118654752f));
        float g1 = 0.5f * t1 * (1.f + erff(t1 * 0.70710678118654752f));
        float g2 = 0.5f * t2 * (1.f + erff(t2 * 0.70710678118654752f));
        float g3 = 0.5f * t3 * (1.f + erff(t3 * 0.70710678118654752f));
        *(int2*)&outb[(size_t)gr * MLPD + gcb] =
            make_int2((int)pkbf(g0, g1), (int)pkbf(g2, g3));
      } else {
        size_t idx = (size_t)gr * DIMC + gcb;
        float4 ad = *(const float4*)&addin[idx];
        *(float4*)&outf[idx] = make_float4(t0 + ad.x, t1 + ad.y, t2 + ad.z, t3 + ad.w);
      }
    }
  }
}

// ---------- 32x32 MFMA attention: in-register P, defer-max online softmax ----------
// q pre-scaled 1/8, relcat x8. Per wave: one 32-q tile; chunk = 32 keys.
// S = mfma(K,Q): col=q=l&31, rows=keys crow(r,hi)=(r&3)+8*(r>>2)+4*hi.
template <bool TAIL>
__device__ __forceinline__ void attn_chunk(
    int kk, int l31, int hi,
    const unsigned short* __restrict__ kg,
    const unsigned short* __restrict__ VT,
    const short8* qf, const short8* qrel,
    f32x16& olo, f32x16& ohi_, float& m_reg, float& s_run) {
  int key = kk * 32 + l31;
  int keyc = (TAIL && key > 195) ? 195 : key;
  f32x16 S = {};
  __builtin_amdgcn_s_setprio(1);
  #pragma unroll
  for (int m = 0; m < 4; m++) {
    short8 kf = *(const short8*)(kg + (size_t)keyc * 64 + m * 16 + hi * 8);
    S = __builtin_amdgcn_mfma_f32_32x32x16_bf16(kf, qf[m], S, 0, 0, 0);
  }
  {
    int ki = keyc / 14, kj = keyc - ki * 14;
    #pragma unroll
    for (int m2 = 0; m2 < 2; m2++) {
      short8 kh;
      #pragma unroll
      for (int j = 0; j < 8; j++) {
        int cc = m2 * 16 + hi * 8 + j;
        kh[j] = (short)((cc == ki || cc == 14 + kj) ? 0x3F80 : 0);
      }
      S = __builtin_amdgcn_mfma_f32_32x32x16_bf16(kh, qrel[m2], S, 0, 0, 0);
    }
  }
  __builtin_amdgcn_s_setprio(0);
  // mask + chunk max (per q-col = l31)
  float pmax = -3e38f;
  #pragma unroll
  for (int r = 0; r < 16; r++) {
    if (TAIL) {
      int krow = kk * 32 + (r & 3) + 8 * (r >> 2) + 4 * hi;
      if (krow >= 196) S[r] = -3e38f;
    }
    pmax = fmaxf(pmax, S[r]);
  }
  pmax = fmaxf(pmax, __shfl_xor(pmax, 32));
  if (__any(pmax > m_reg + 8.f)) {      // defer-max (T13)
    float m_new = fmaxf(m_reg, pmax);
    float fac = __expf(m_reg - m_new);
    m_reg = m_new;
    s_run *= fac;
    #pragma unroll
    for (int r = 0; r < 16; r++) {
      int qr = (r & 3) + 8 * (r >> 2) + 4 * hi;
      float fr_ = __shfl(fac, qr);
      olo[r] *= fr_; ohi_[r] *= fr_;
    }
  }
  float psum = 0.f;
  #pragma unroll
  for (int r = 0; r < 16; r++) { S[r] = __expf(S[r] - m_reg); psum += S[r]; }
  s_run += psum;
  // pack P into PV A-fragments (in-register, cvt_pk + shfl_xor(32) + select)
  unsigned int pk[8];
  #pragma unroll
  for (int t = 0; t < 8; t++) pk[t] = pkbf(S[2 * t], S[2 * t + 1]);
  #pragma unroll
  for (int m2 = 0; m2 < 2; m2++) {
    int b_ = m2 * 4;
    unsigned int x0 = (unsigned int)__shfl_xor((int)pk[b_ + 0], 32);
    unsigned int x1 = (unsigned int)__shfl_xor((int)pk[b_ + 1], 32);
    unsigned int x2 = (unsigned int)__shfl_xor((int)pk[b_ + 2], 32);
    unsigned int x3 = (unsigned int)__shfl_xor((int)pk[b_ + 3], 32);
    unsigned int au[4];
    au[0] = hi ? x2 : pk[b_ + 0];
    au[1] = hi ? x3 : pk[b_ + 1];
    au[2] = hi ? pk[b_ + 2] : x0;
    au[3] = hi ? pk[b_ + 3] : x1;
    short8 pa; __builtin_memcpy(&pa, au, 16);
    int kb = kk * 32 + m2 * 16 + hi * 8;
    if (TAIL && kb > 208) kb = 208;      // zero VT cols; P there is 0 anyway
    short8 vblo = *(const short8*)&VT[l31 * 216 + kb];
    short8 vbhi = *(const short8*)&VT[(32 + l31) * 216 + kb];
    __builtin_amdgcn_s_setprio(1);
    olo  = __builtin_amdgcn_mfma_f32_32x32x16_bf16(pa, vblo, olo, 0, 0, 0);
    ohi_ = __builtin_amdgcn_mfma_f32_32x32x16_bf16(pa, vbhi, ohi_, 0, 0, 0);
    __builtin_amdgcn_s_setprio(0);
  }
}

__global__ __launch_bounds__(256) void attn32_kernel(
    const unsigned short* __restrict__ qk_g,   // [2][1200][196][64] bf16
    const unsigned short* __restrict__ vT_g,   // [1200][64][208] bf16 (cols 196..207 zeroed)
    const unsigned short* __restrict__ relcat, // [64][64] bf16 (x8)
    unsigned short* __restrict__ attnout) {    // [200*196][384] bf16
  __shared__ __align__(16) unsigned short VT[64 * 216];   // cols 196..215 zero
  __shared__ __align__(16) unsigned short RELB[4][2048];  // per-wave [q 0..31][relrow 0..63]
  const int wh = blockIdx.x;
  const int w = wh / NHD, h = wh - w * NHD;
  const int tid = threadIdx.x;
  const unsigned short* vrow = vT_g + (size_t)wh * 64 * 208;
  for (int e = tid; e < 64 * 27; e += 256) {
    int d = e / 27, c = e - d * 27;
    int4 val = {0, 0, 0, 0};
    if (c < 26) val = *(const int4*)(vrow + d * 208 + c * 8);
    *(int4*)&VT[d * 216 + c * 8] = val;
  }
  __syncthreads();
  const int l = tid & 63, wv = tid >> 6;
  const int l31 = l & 31, hi = l >> 5;
  unsigned short* RB = &RELB[wv][0];
  const unsigned short* qg = qk_g + (size_t)wh * (NTOK * 64);
  const unsigned short* kg = qk_g + (size_t)(NWH + wh) * (NTOK * 64);

  for (int tile = wv; tile < 7; tile += 4) {
    const int q0 = tile * 32;
    int qrow = q0 + l31; if (qrow > 195) qrow = 195;
    short8 qf[4];
    #pragma unroll
    for (int m = 0; m < 4; m++)
      qf[m] = *(const short8*)(qg + (size_t)qrow * 64 + m * 16 + hi * 8);
    // RELB = relcat . Q^T (col=q, rows=relrow), packed-pair stores
    #pragma unroll
    for (int rt = 0; rt < 2; rt++) {
      f32x16 cr = {};
      __builtin_amdgcn_s_setprio(1);
      #pragma unroll
      for (int m = 0; m < 4; m++) {
        short8 af = *(const short8*)(relcat + (rt * 32 + l31) * 64 + m * 16 + hi * 8);
        cr = __builtin_amdgcn_mfma_f32_32x32x16_bf16(af, qf[m], cr, 0, 0, 0);
      }
      __builtin_amdgcn_s_setprio(0);
      #pragma unroll
      for (int t = 0; t < 8; t++) {
        int rr = rt * 32 + ((2 * t) & 3) + 8 * (t >> 1) + 4 * hi;
        *(unsigned int*)&RB[l31 * 64 + rr] = pkbf(cr[2 * t], cr[2 * t + 1]);
      }
    }
    __builtin_amdgcn_wave_barrier();
    // gather qrel per lane: c = m2*16 + hi*8 + j
    int qi = qrow / 14, qj = qrow - qi * 14;
    short8 qrel[2];
    #pragma unroll
    for (int m2 = 0; m2 < 2; m2++)
      #pragma unroll
      for (int j = 0; j < 8; j++) {
        int cc = m2 * 16 + hi * 8 + j;
        unsigned short vv = 0;
        if (cc < 14) vv = RB[l31 * 64 + (qi - cc + 13)];
        else if (cc < 28) vv = RB[l31 * 64 + 27 + (qj - (cc - 14) + 13)];
        qrel[m2][j] = (short)vv;
      }
    __builtin_amdgcn_wave_barrier();
    // online chunks
    f32x16 olo = {}, ohi_ = {};
    float m_reg = -3e38f, s_run = 0.f;
    for (int kk = 0; kk < 6; kk++)
      attn_chunk<false>(kk, l31, hi, kg, VT, qf, qrel, olo, ohi_, m_reg, s_run);
    attn_chunk<true>(6, l31, hi, kg, VT, qf, qrel, olo, ohi_, m_reg, s_run);
    // finalize
    s_run += __shfl_xor(s_run, 32);
    float inv = 1.f / s_run;
    #pragma unroll
    for (int r = 0; r < 16; r++) {
      int qr = (r & 3) + 8 * (r >> 2) + 4 * hi;
      float ir = __shfl(inv, qr);
      int tok = q0 + qr;
      if (tok < 196) {
        size_t base = ((size_t)w * NTOK + tok) * DIMC + h * 64;
        attnout[base + l31] = f2bf(olo[r] * ir);
        attnout[base + 32 + l31] = f2bf(ohi_[r] * ir);
      }
    }
  }
}

extern "C" void kernel_launch(void* const* d_in, const int* in_sizes, int n_in,
                              void* d_out, int out_size, void* d_ws, size_t ws_size,
                              hipStream_t stream) {
  const float* x     = (const float*)d_in[0];
  const float* ln1w  = (const float*)d_in[1];
  const float* ln1b  = (const float*)d_in[2];
  const float* qkvw  = (const float*)d_in[3];
  const float* qkvb  = (const float*)d_in[4];
  const float* projw = (const float*)d_in[5];
  const float* projb = (const float*)d_in[6];
  const float* relh  = (const float*)d_in[7];
  const float* relw  = (const float*)d_in[8];
  const float* ln2w  = (const float*)d_in[9];
  const float* ln2b  = (const float*)d_in[10];
  const float* fc1w  = (const float*)d_in[11];
  const float* fc1b  = (const float*)d_in[12];
  const float* fc2w  = (const float*)d_in[13];
  const float* fc2b  = (const float*)d_in[14];

  const size_t R0 = 0;
  const size_t R1 = R0 + 50331648;
  const size_t R2 = R1 + 100663296;
  const size_t R3 = R2 + 30105600;
  const size_t NEED = R3 + 3547136;
  if (ws_size < NEED) return;
  char* ws = (char*)d_ws;
  unsigned short* xw     = (unsigned short*)(ws + R0);
  float*          x2     = (float*)(ws + R0);
  unsigned short* qk_g   = (unsigned short*)(ws + R1);
  unsigned short* vT_g   = qk_g + (size_t)2 * NWH * NTOK * 64;
  unsigned short* hidden = (unsigned short*)(ws + R1);
  unsigned short* attno  = (unsigned short*)(ws + R2);
  unsigned short* h2     = (unsigned short*)(ws + R2);
  unsigned short* qkvwT  = (unsigned short*)(ws + R3);
  unsigned short* projwT = qkvwT + 442368;
  unsigned short* fc1wT  = projwT + 147456;
  unsigned short* fc2wT  = fc1wT + 589824;
  unsigned short* relcat = fc2wT + 589824;

  wtrans_kernel<<<1728, 256, 0, stream>>>(qkvw, qkvwT, 384, 1152);
  wtrans_kernel<<<576, 256, 0, stream>>>(projw, projwT, 384, 384);
  wtrans_kernel<<<2304, 256, 0, stream>>>(fc1w, fc1wT, 384, 1536);
  wtrans_kernel<<<2304, 256, 0, stream>>>(fc2w, fc2wT, 1536, 384);
  relprep_kernel<<<16, 256, 0, stream>>>(relh, relw, relcat);
  vpad_kernel<<<900, 256, 0, stream>>>(vT_g);
  ln1win_kernel<<<MWIN, 64, 0, stream>>>(x, ln1w, ln1b, xw);
  gemm_kernel<0><<<dim3(307, 9), 256, 0, stream>>>(xw, qkvwT, MWIN, 384, qkvb, nullptr, nullptr, qk_g, vT_g);
  attn32_kernel<<<NWH, 256, 0, stream>>>(qk_g, vT_g, relcat, attno);
  gemm_kernel<1><<<dim3(307, 3), 256, 0, stream>>>(attno, projwT, MWIN, 384, projb, x, x2, nullptr, nullptr);
  ln2_kernel<<<MX, 64, 0, stream>>>(x2, ln2w, ln2b, h2);
  gemm_kernel<2><<<dim3(256, 12), 256, 0, stream>>>(h2, fc1wT, MX, 384, fc1b, nullptr, nullptr, hidden, nullptr);
  gemm_kernel<3><<<dim3(256, 3), 256, 0, stream>>>(hidden, fc2wT, MX, 1536, fc2b, x2, (float*)d_out, nullptr, nullptr);
}

// Round 8
// 361.232 us; speedup vs baseline: 1.7521x; 1.0778x over previous
//
#include <hip/hip_runtime.h>
#include <math.h>

#define DIMC 384
#define NHD  6
#define HD   64
#define WSZ  14
#define NTOK 196
#define NWIN 200
#define NWH  1200
#define MWIN 39200
#define MX   32768
#define MLPD 1536

typedef short short8 __attribute__((ext_vector_type(8)));
typedef float f32x4 __attribute__((ext_vector_type(4)));
typedef float f32x16 __attribute__((ext_vector_type(16)));

__device__ __forceinline__ unsigned short f2bf(float f) {
  unsigned int u = __float_as_uint(f);
  u = (u + 0x7fffu + ((u >> 16) & 1u)) >> 16;
  return (unsigned short)u;
}
__device__ __forceinline__ unsigned int pkbf(float a, float b) {
  unsigned int r; asm("v_cvt_pk_bf16_f32 %0, %1, %2" : "=v"(r) : "v"(a), "v"(b)); return r;
}
// tanh-GELU (|err| <= ~3e-3 abs vs exact erf form; well under bf16 tolerance here)
__device__ __forceinline__ float gelu_t(float x) {
  float z = 1.5957691216057308f * (x + 0.044715f * x * x * x);  // 2*sqrt(2/pi)*(...)
  float e = __expf(z);
  float th = 1.f - 2.f * __builtin_amdgcn_rcpf(e + 1.f);        // tanh(z/2)
  return 0.5f * x * (1.f + th);
}

typedef const __attribute__((address_space(1))) unsigned int* gptr_t;
typedef __attribute__((address_space(3))) unsigned int* lptr_t;
__device__ __forceinline__ void gload16(const unsigned short* g, unsigned short* l) {
  __builtin_amdgcn_global_load_lds((gptr_t)(const void*)g, (lptr_t)(void*)l, 16, 0, 0);
}

// ---------- weight transpose + bf16 convert ----------
__global__ void wtrans_kernel(const float* __restrict__ in, unsigned short* __restrict__ out,
                              int K, int N) {
  int id = blockIdx.x * 256 + threadIdx.x;
  if (id >= K * N) return;
  int n = id / K, k = id - n * K;
  out[id] = f2bf(in[(size_t)k * N + n]);
}

// ---------- relcat x8: rows 0..26 = 8*relh, 27..53 = 8*relw, rest 0 ----------
__global__ void relprep_kernel(const float* __restrict__ relh, const float* __restrict__ relw,
                               unsigned short* __restrict__ relcat) {
  int id = blockIdx.x * 256 + threadIdx.x;
  if (id >= 64 * 64) return;
  int rc = id >> 6, d = id & 63;
  float v = 0.f;
  if (rc < 27) v = relh[rc * 64 + d] * 8.f;
  else if (rc < 54) v = relw[(rc - 27) * 64 + d] * 8.f;
  relcat[id] = f2bf(v);
}

// ---------- zero vT pad columns 196..207 ----------
__global__ void vpad_kernel(unsigned short* __restrict__ vT) {
  int id = blockIdx.x * 256 + threadIdx.x;
  if (id >= 76800 * 3) return;
  int row = id / 3, part = id - row * 3;
  *(int2*)(vT + (size_t)row * 208 + 196 + part * 4) = make_int2(0, 0);
}

// ---------- LN1 + window partition ----------
__global__ __launch_bounds__(64) void ln1win_kernel(const float* __restrict__ x,
    const float* __restrict__ w, const float* __restrict__ b, unsigned short* __restrict__ xw) {
  int t = blockIdx.x;
  int lane = threadIdx.x;
  int win = t / NTOK, p = t - win * NTOK;
  int bb = win / 25, rem = win - bb * 25;
  int wi = rem / 5, wj = rem - wi * 5;
  int i = p / WSZ, j = p - i * WSZ;
  int r = wi * WSZ + i, c = wj * WSZ + j;
  unsigned short* o = xw + (size_t)t * DIMC;
  if (r >= 64 || c >= 64) {
    #pragma unroll
    for (int q = 0; q < 6; q++) o[lane + q * 64] = 0;
    return;
  }
  const float* xr = x + (((size_t)bb * 64 + r) * 64 + c) * DIMC;
  float v[6]; float s = 0.f, s2 = 0.f;
  #pragma unroll
  for (int q = 0; q < 6; q++) { float f = xr[lane + q * 64]; v[q] = f; s += f; s2 += f * f; }
  #pragma unroll
  for (int off = 32; off; off >>= 1) { s += __shfl_xor(s, off); s2 += __shfl_xor(s2, off); }
  float mean = s * (1.f / DIMC);
  float var  = s2 * (1.f / DIMC) - mean * mean;
  float rstd = rsqrtf(var + 1e-5f);
  #pragma unroll
  for (int q = 0; q < 6; q++) {
    int d = lane + q * 64;
    o[d] = f2bf((v[q] - mean) * rstd * w[d] + b[d]);
  }
}

// ---------- LN2 ----------
__global__ __launch_bounds__(64) void ln2_kernel(const float* __restrict__ x2,
    const float* __restrict__ w, const float* __restrict__ b, unsigned short* __restrict__ h2) {
  int t = blockIdx.x; int lane = threadIdx.x;
  const float* xr = x2 + (size_t)t * DIMC;
  unsigned short* o = h2 + (size_t)t * DIMC;
  float v[6]; float s = 0.f, s2 = 0.f;
  #pragma unroll
  for (int q = 0; q < 6; q++) { float f = xr[lane + q * 64]; v[q] = f; s += f; s2 += f * f; }
  #pragma unroll
  for (int off = 32; off; off >>= 1) { s += __shfl_xor(s, off); s2 += __shfl_xor(s2, off); }
  float mean = s * (1.f / DIMC);
  float var  = s2 * (1.f / DIMC) - mean * mean;
  float rstd = rsqrtf(var + 1e-5f);
  #pragma unroll
  for (int q = 0; q < 6; q++) {
    int d = lane + q * 64;
    o[d] = f2bf((v[q] - mean) * rstd * w[d] + b[d]);
  }
}

// ---------- bf16 MFMA GEMM: double-buffered stage (2-phase), swizzled LDS, XCD remap ----------
template <int EPI>
__global__ __launch_bounds__(256) void gemm_kernel(
    const unsigned short* __restrict__ A, const unsigned short* __restrict__ WT,
    int Mrows, int Kd,
    const float* __restrict__ bias, const float* __restrict__ addin,
    float* __restrict__ outf, unsigned short* __restrict__ outb,
    unsigned short* __restrict__ outb2) {
  __shared__ unsigned short As[2][128 * 32];
  __shared__ unsigned short Bs[2][128 * 32];
  // XCD-aware bijective remap (m204)
  const int nwg = gridDim.x * gridDim.y;
  const int flat = blockIdx.y * gridDim.x + blockIdx.x;
  const int xcd = flat & 7, q_ = nwg >> 3, r_ = nwg & 7;
  const int wg = (xcd < r_ ? xcd * (q_ + 1) : r_ * (q_ + 1) + (xcd - r_) * q_) + (flat >> 3);
  const int bx = wg / gridDim.y, by = wg - bx * gridDim.y;
  const int row0 = bx * 128, col0 = by * 128;
  const int tid = threadIdx.x;
  const int l = tid & 63, wid = tid >> 6;
  const int fr = l & 15, fk = (l >> 4) * 8;
  const int wr = (wid >> 1) * 64, wc = (wid & 1) * 64;
  const int sr = l >> 2, sc = (l & 3) * 8;
  const int scs = sc ^ (((sr >> 1) & 3) << 3);   // source col swizzle (shorts)
  const int rsw = ((fr >> 1) & 3) << 3;          // read col swizzle
  f32x4 acc[4][4] = {};
  const unsigned short* ap = A + (size_t)row0 * Kd;
  const unsigned short* bp = WT + (size_t)col0 * Kd;
  const int nt = Kd >> 5;
  // prologue: stage tile 0 into buffer 0
  #pragma unroll
  for (int j = 0; j < 2; j++) {
    int chunk = j * 4 + wid;
    gload16(ap + (size_t)(chunk * 16 + sr) * Kd + scs, &As[0][chunk * 512]);
    gload16(bp + (size_t)(chunk * 16 + sr) * Kd + scs, &Bs[0][chunk * 512]);
  }
  __syncthreads();
  int cur = 0;
  for (int t = 0; t < nt; ++t) {
    if (t + 1 < nt) {
      const int k0 = (t + 1) * 32;
      #pragma unroll
      for (int j = 0; j < 2; j++) {
        int chunk = j * 4 + wid;
        gload16(ap + (size_t)(chunk * 16 + sr) * Kd + k0 + scs, &As[cur ^ 1][chunk * 512]);
        gload16(bp + (size_t)(chunk * 16 + sr) * Kd + k0 + scs, &Bs[cur ^ 1][chunk * 512]);
      }
    }
    short8 a[4], b[4];
    #pragma unroll
    for (int fi = 0; fi < 4; fi++) {
      a[fi] = *(const short8*)&As[cur][(wr + fi * 16 + fr) * 32 + (fk ^ rsw)];
      b[fi] = *(const short8*)&Bs[cur][(wc + fi * 16 + fr) * 32 + (fk ^ rsw)];
    }
    #pragma unroll
    for (int fi = 0; fi < 4; fi++)
      #pragma unroll
      for (int fj = 0; fj < 4; fj++)
        acc[fi][fj] = __builtin_amdgcn_mfma_f32_16x16x32_bf16(b[fj], a[fi], acc[fi][fj], 0, 0, 0);
    __syncthreads();   // drains vmcnt(0): overlapped with the ds_read+MFMA above
    cur ^= 1;
  }
  #pragma unroll
  for (int fi = 0; fi < 4; fi++) {
    const int gr = row0 + wr + fi * 16 + fr;
    if (gr >= Mrows) continue;
    int wv_ = 0, p = 0, valid = 1; size_t pixbase = 0;
    if (EPI == 0 || EPI == 1) { wv_ = gr / NTOK; p = gr - wv_ * NTOK; }
    if (EPI == 1) {
      int bb = wv_ / 25, rem2 = wv_ - bb * 25;
      int wi = rem2 / 5, wj = rem2 - wi * 5;
      int i = p / WSZ, j = p - i * WSZ;
      int rr = wi * WSZ + i, cc = wj * WSZ + j;
      valid = (rr < 64) && (cc < 64);
      pixbase = (((size_t)bb * 64 + rr) * 64 + cc) * DIMC;
    }
    #pragma unroll
    for (int fj = 0; fj < 4; fj++) {
      const int gcb = col0 + wc + fj * 16 + (l >> 4) * 4;
      f32x4 v = acc[fi][fj];
      float4 bv = *(const float4*)&bias[gcb];
      float t0 = v[0] + bv.x, t1 = v[1] + bv.y, t2 = v[2] + bv.z, t3 = v[3] + bv.w;
      if (EPI == 0) {
        int s = gcb / 384, rem = gcb - s * 384;
        int hh = rem >> 6, d0 = gcb & 63;
        int whh = wv_ * NHD + hh;
        if (s == 0) { t0 *= 0.125f; t1 *= 0.125f; t2 *= 0.125f; t3 *= 0.125f; }
        if (s < 2) {
          *(int2*)&outb[((size_t)s * NWH + whh) * (NTOK * 64) + p * 64 + d0] =
              make_int2((int)pkbf(t0, t1), (int)pkbf(t2, t3));
        } else {
          unsigned short* vb = outb2 + ((size_t)whh * 64 + d0) * 208 + p;
          vb[0] = f2bf(t0); vb[208] = f2bf(t1); vb[416] = f2bf(t2); vb[624] = f2bf(t3);
        }
      } else if (EPI == 1) {
        if (valid) {
          size_t idx = pixbase + gcb;
          float4 ad = *(const float4*)&addin[idx];
          *(float4*)&outf[idx] = make_float4(t0 + ad.x, t1 + ad.y, t2 + ad.z, t3 + ad.w);
        }
      } else if (EPI == 2) {
        *(int2*)&outb[(size_t)gr * MLPD + gcb] =
            make_int2((int)pkbf(gelu_t(t0), gelu_t(t1)), (int)pkbf(gelu_t(t2), gelu_t(t3)));
      } else {
        size_t idx = (size_t)gr * DIMC + gcb;
        float4 ad = *(const float4*)&addin[idx];
        *(float4*)&outf[idx] = make_float4(t0 + ad.x, t1 + ad.y, t2 + ad.z, t3 + ad.w);
      }
    }
  }
}

// ---------- 32x32 MFMA attention: in-register P, defer-max online softmax ----------
template <bool TAIL>
__device__ __forceinline__ void attn_chunk(
    int kk, int l31, int hi,
    const unsigned short* __restrict__ kg,
    const unsigned short* __restrict__ VT,
    const short8* qf, const short8* qrel,
    f32x16& olo, f32x16& ohi_, float& m_reg, float& s_run) {
  int key = kk * 32 + l31;
  int keyc = (TAIL && key > 195) ? 195 : key;
  f32x16 S = {};
  __builtin_amdgcn_s_setprio(1);
  #pragma unroll
  for (int m = 0; m < 4; m++) {
    short8 kf = *(const short8*)(kg + (size_t)keyc * 64 + m * 16 + hi * 8);
    S = __builtin_amdgcn_mfma_f32_32x32x16_bf16(kf, qf[m], S, 0, 0, 0);
  }
  {
    int ki = keyc / 14, kj = keyc - ki * 14;
    #pragma unroll
    for (int m2 = 0; m2 < 2; m2++) {
      short8 kh;
      #pragma unroll
      for (int j = 0; j < 8; j++) {
        int cc = m2 * 16 + hi * 8 + j;
        kh[j] = (short)((cc == ki || cc == 14 + kj) ? 0x3F80 : 0);
      }
      S = __builtin_amdgcn_mfma_f32_32x32x16_bf16(kh, qrel[m2], S, 0, 0, 0);
    }
  }
  __builtin_amdgcn_s_setprio(0);
  float pmax = -3e38f;
  #pragma unroll
  for (int r = 0; r < 16; r++) {
    if (TAIL) {
      int krow = kk * 32 + (r & 3) + 8 * (r >> 2) + 4 * hi;
      if (krow >= 196) S[r] = -3e38f;
    }
    pmax = fmaxf(pmax, S[r]);
  }
  pmax = fmaxf(pmax, __shfl_xor(pmax, 32));
  if (__any(pmax > m_reg + 8.f)) {
    float m_new = fmaxf(m_reg, pmax);
    float fac = __expf(m_reg - m_new);
    m_reg = m_new;
    s_run *= fac;
    #pragma unroll
    for (int r = 0; r < 16; r++) {
      int qr = (r & 3) + 8 * (r >> 2) + 4 * hi;
      float fr_ = __shfl(fac, qr);
      olo[r] *= fr_; ohi_[r] *= fr_;
    }
  }
  float psum = 0.f;
  #pragma unroll
  for (int r = 0; r < 16; r++) { S[r] = __expf(S[r] - m_reg); psum += S[r]; }
  s_run += psum;
  unsigned int pk[8];
  #pragma unroll
  for (int t = 0; t < 8; t++) pk[t] = pkbf(S[2 * t], S[2 * t + 1]);
  #pragma unroll
  for (int m2 = 0; m2 < 2; m2++) {
    int b_ = m2 * 4;
    unsigned int x0 = (unsigned int)__shfl_xor((int)pk[b_ + 0], 32);
    unsigned int x1 = (unsigned int)__shfl_xor((int)pk[b_ + 1], 32);
    unsigned int x2 = (unsigned int)__shfl_xor((int)pk[b_ + 2], 32);
    unsigned int x3 = (unsigned int)__shfl_xor((int)pk[b_ + 3], 32);
    unsigned int au[4];
    au[0] = hi ? x2 : pk[b_ + 0];
    au[1] = hi ? x3 : pk[b_ + 1];
    au[2] = hi ? pk[b_ + 2] : x0;
    au[3] = hi ? pk[b_ + 3] : x1;
    short8 pa; __builtin_memcpy(&pa, au, 16);
    int kb = kk * 32 + m2 * 16 + hi * 8;
    if (TAIL && kb > 208) kb = 208;
    short8 vblo = *(const short8*)&VT[l31 * 216 + kb];
    short8 vbhi = *(const short8*)&VT[(32 + l31) * 216 + kb];
    __builtin_amdgcn_s_setprio(1);
    olo  = __builtin_amdgcn_mfma_f32_32x32x16_bf16(pa, vblo, olo, 0, 0, 0);
    ohi_ = __builtin_amdgcn_mfma_f32_32x32x16_bf16(pa, vbhi, ohi_, 0, 0, 0);
    __builtin_amdgcn_s_setprio(0);
  }
}

__global__ __launch_bounds__(256) void attn32_kernel(
    const unsigned short* __restrict__ qk_g,
    const unsigned short* __restrict__ vT_g,
    const unsigned short* __restrict__ relcat,
    unsigned short* __restrict__ attnout) {
  __shared__ __align__(16) unsigned short VT[64 * 216];
  __shared__ __align__(16) unsigned short RELB[4][2048];
  const int wh = blockIdx.x;
  const int w = wh / NHD, h = wh - w * NHD;
  const int tid = threadIdx.x;
  const unsigned short* vrow = vT_g + (size_t)wh * 64 * 208;
  for (int e = tid; e < 64 * 27; e += 256) {
    int d = e / 27, c = e - d * 27;
    int4 val = {0, 0, 0, 0};
    if (c < 26) val = *(const int4*)(vrow + d * 208 + c * 8);
    *(int4*)&VT[d * 216 + c * 8] = val;
  }
  __syncthreads();
  const int l = tid & 63, wv = tid >> 6;
  const int l31 = l & 31, hi = l >> 5;
  unsigned short* RB = &RELB[wv][0];
  const unsigned short* qg = qk_g + (size_t)wh * (NTOK * 64);
  const unsigned short* kg = qk_g + (size_t)(NWH + wh) * (NTOK * 64);

  for (int tile = wv; tile < 7; tile += 4) {
    const int q0 = tile * 32;
    int qrow = q0 + l31; if (qrow > 195) qrow = 195;
    short8 qf[4];
    #pragma unroll
    for (int m = 0; m < 4; m++)
      qf[m] = *(const short8*)(qg + (size_t)qrow * 64 + m * 16 + hi * 8);
    #pragma unroll
    for (int rt = 0; rt < 2; rt++) {
      f32x16 cr = {};
      __builtin_amdgcn_s_setprio(1);
      #pragma unroll
      for (int m = 0; m < 4; m++) {
        short8 af = *(const short8*)(relcat + (rt * 32 + l31) * 64 + m * 16 + hi * 8);
        cr = __builtin_amdgcn_mfma_f32_32x32x16_bf16(af, qf[m], cr, 0, 0, 0);
      }
      __builtin_amdgcn_s_setprio(0);
      #pragma unroll
      for (int t = 0; t < 8; t++) {
        int rr = rt * 32 + ((2 * t) & 3) + 8 * (t >> 1) + 4 * hi;
        *(unsigned int*)&RB[l31 * 64 + rr] = pkbf(cr[2 * t], cr[2 * t + 1]);
      }
    }
    __builtin_amdgcn_wave_barrier();
    int qi = qrow / 14, qj = qrow - qi * 14;
    short8 qrel[2];
    #pragma unroll
    for (int m2 = 0; m2 < 2; m2++)
      #pragma unroll
      for (int j = 0; j < 8; j++) {
        int cc = m2 * 16 + hi * 8 + j;
        unsigned short vv = 0;
        if (cc < 14) vv = RB[l31 * 64 + (qi - cc + 13)];
        else if (cc < 28) vv = RB[l31 * 64 + 27 + (qj - (cc - 14) + 13)];
        qrel[m2][j] = (short)vv;
      }
    __builtin_amdgcn_wave_barrier();
    f32x16 olo = {}, ohi_ = {};
    float m_reg = -3e38f, s_run = 0.f;
    for (int kk = 0; kk < 6; kk++)
      attn_chunk<false>(kk, l31, hi, kg, VT, qf, qrel, olo, ohi_, m_reg, s_run);
    attn_chunk<true>(6, l31, hi, kg, VT, qf, qrel, olo, ohi_, m_reg, s_run);
    s_run += __shfl_xor(s_run, 32);
    float inv = 1.f / s_run;
    #pragma unroll
    for (int r = 0; r < 16; r++) {
      int qr = (r & 3) + 8 * (r >> 2) + 4 * hi;
      float ir = __shfl(inv, qr);
      int tok = q0 + qr;
      if (tok < 196) {
        size_t base = ((size_t)w * NTOK + tok) * DIMC + h * 64;
        attnout[base + l31] = f2bf(olo[r] * ir);
        attnout[base + 32 + l31] = f2bf(ohi_[r] * ir);
      }
    }
  }
}

extern "C" void kernel_launch(void* const* d_in, const int* in_sizes, int n_in,
                              void* d_out, int out_size, void* d_ws, size_t ws_size,
                              hipStream_t stream) {
  const float* x     = (const float*)d_in[0];
  const float* ln1w  = (const float*)d_in[1];
  const float* ln1b  = (const float*)d_in[2];
  const float* qkvw  = (const float*)d_in[3];
  const float* qkvb  = (const float*)d_in[4];
  const float* projw = (const float*)d_in[5];
  const float* projb = (const float*)d_in[6];
  const float* relh  = (const float*)d_in[7];
  const float* relw  = (const float*)d_in[8];
  const float* ln2w  = (const float*)d_in[9];
  const float* ln2b  = (const float*)d_in[10];
  const float* fc1w  = (const float*)d_in[11];
  const float* fc1b  = (const float*)d_in[12];
  const float* fc2w  = (const float*)d_in[13];
  const float* fc2b  = (const float*)d_in[14];

  const size_t R0 = 0;
  const size_t R1 = R0 + 50331648;
  const size_t R2 = R1 + 100663296;
  const size_t R3 = R2 + 30105600;
  const size_t NEED = R3 + 3547136;
  if (ws_size < NEED) return;
  char* ws = (char*)d_ws;
  unsigned short* xw     = (unsigned short*)(ws + R0);
  float*          x2     = (float*)(ws + R0);
  unsigned short* qk_g   = (unsigned short*)(ws + R1);
  unsigned short* vT_g   = qk_g + (size_t)2 * NWH * NTOK * 64;
  unsigned short* hidden = (unsigned short*)(ws + R1);
  unsigned short* attno  = (unsigned short*)(ws + R2);
  unsigned short* h2     = (unsigned short*)(ws + R2);
  unsigned short* qkvwT  = (unsigned short*)(ws + R3);
  unsigned short* projwT = qkvwT + 442368;
  unsigned short* fc1wT  = projwT + 147456;
  unsigned short* fc2wT  = fc1wT + 589824;
  unsigned short* relcat = fc2wT + 589824;

  wtrans_kernel<<<1728, 256, 0, stream>>>(qkvw, qkvwT, 384, 1152);
  wtrans_kernel<<<576, 256, 0, stream>>>(projw, projwT, 384, 384);
  wtrans_kernel<<<2304, 256, 0, stream>>>(fc1w, fc1wT, 384, 1536);
  wtrans_kernel<<<2304, 256, 0, stream>>>(fc2w, fc2wT, 1536, 384);
  relprep_kernel<<<16, 256, 0, stream>>>(relh, relw, relcat);
  vpad_kernel<<<900, 256, 0, stream>>>(vT_g);
  ln1win_kernel<<<MWIN, 64, 0, stream>>>(x, ln1w, ln1b, xw);
  gemm_kernel<0><<<dim3(307, 9), 256, 0, stream>>>(xw, qkvwT, MWIN, 384, qkvb, nullptr, nullptr, qk_g, vT_g);
  attn32_kernel<<<NWH, 256, 0, stream>>>(qk_g, vT_g, relcat, attno);
  gemm_kernel<1><<<dim3(307, 3), 256, 0, stream>>>(attno, projwT, MWIN, 384, projb, x, x2, nullptr, nullptr);
  ln2_kernel<<<MX, 64, 0, stream>>>(x2, ln2w, ln2b, h2);
  gemm_kernel<2><<<dim3(256, 12), 256, 0, stream>>>(h2, fc1wT, MX, 384, fc1b, nullptr, nullptr, hidden, nullptr);
  gemm_kernel<3><<<dim3(256, 3), 256, 0, stream>>>(hidden, fc2wT, MX, 1536, fc2b, x2, (float*)d_out, nullptr, nullptr);
}

// Round 9
// 358.140 us; speedup vs baseline: 1.7672x; 1.0086x over previous
//
#include <hip/hip_runtime.h>
#include <math.h>

#define DIMC 384
#define NHD  6
#define HD   64
#define WSZ  14
#define NTOK 196
#define NWIN 200
#define NWH  1200
#define MWIN 39200
#define MX   32768
#define MLPD 1536

typedef short short8 __attribute__((ext_vector_type(8)));
typedef float f32x4 __attribute__((ext_vector_type(4)));
typedef float f32x16 __attribute__((ext_vector_type(16)));

__device__ __forceinline__ unsigned short f2bf(float f) {
  unsigned int u = __float_as_uint(f);
  u = (u + 0x7fffu + ((u >> 16) & 1u)) >> 16;
  return (unsigned short)u;
}
__device__ __forceinline__ unsigned int pkbf(float a, float b) {
  unsigned int r; asm("v_cvt_pk_bf16_f32 %0, %1, %2" : "=v"(r) : "v"(a), "v"(b)); return r;
}
// tanh-GELU (|err| <= ~3e-3 abs; well under tolerance here)
__device__ __forceinline__ float gelu_t(float x) {
  float z = 1.5957691216057308f * (x + 0.044715f * x * x * x);
  float e = __expf(z);
  float th = 1.f - 2.f * __builtin_amdgcn_rcpf(e + 1.f);
  return 0.5f * x * (1.f + th);
}

typedef const __attribute__((address_space(1))) unsigned int* gptr_t;
typedef __attribute__((address_space(3))) unsigned int* lptr_t;
__device__ __forceinline__ void gload16(const unsigned short* g, unsigned short* l) {
  __builtin_amdgcn_global_load_lds((gptr_t)(const void*)g, (lptr_t)(void*)l, 16, 0, 0);
}

// ---------- weight transpose + bf16 convert ----------
__global__ void wtrans_kernel(const float* __restrict__ in, unsigned short* __restrict__ out,
                              int K, int N) {
  int id = blockIdx.x * 256 + threadIdx.x;
  if (id >= K * N) return;
  int n = id / K, k = id - n * K;
  out[id] = f2bf(in[(size_t)k * N + n]);
}

// ---------- relcat x8: rows 0..26 = 8*relh, 27..53 = 8*relw, rest 0 ----------
__global__ void relprep_kernel(const float* __restrict__ relh, const float* __restrict__ relw,
                               unsigned short* __restrict__ relcat) {
  int id = blockIdx.x * 256 + threadIdx.x;
  if (id >= 64 * 64) return;
  int rc = id >> 6, d = id & 63;
  float v = 0.f;
  if (rc < 27) v = relh[rc * 64 + d] * 8.f;
  else if (rc < 54) v = relw[(rc - 27) * 64 + d] * 8.f;
  relcat[id] = f2bf(v);
}

// ---------- zero vT pad columns 196..207 ----------
__global__ void vpad_kernel(unsigned short* __restrict__ vT) {
  int id = blockIdx.x * 256 + threadIdx.x;
  if (id >= 76800 * 3) return;
  int row = id / 3, part = id - row * 3;
  *(int2*)(vT + (size_t)row * 208 + 196 + part * 4) = make_int2(0, 0);
}

// ---------- LN1 + window partition ----------
__global__ __launch_bounds__(64) void ln1win_kernel(const float* __restrict__ x,
    const float* __restrict__ w, const float* __restrict__ b, unsigned short* __restrict__ xw) {
  int t = blockIdx.x;
  int lane = threadIdx.x;
  int win = t / NTOK, p = t - win * NTOK;
  int bb = win / 25, rem = win - bb * 25;
  int wi = rem / 5, wj = rem - wi * 5;
  int i = p / WSZ, j = p - i * WSZ;
  int r = wi * WSZ + i, c = wj * WSZ + j;
  unsigned short* o = xw + (size_t)t * DIMC;
  if (r >= 64 || c >= 64) {
    #pragma unroll
    for (int q = 0; q < 6; q++) o[lane + q * 64] = 0;
    return;
  }
  const float* xr = x + (((size_t)bb * 64 + r) * 64 + c) * DIMC;
  float v[6]; float s = 0.f, s2 = 0.f;
  #pragma unroll
  for (int q = 0; q < 6; q++) { float f = xr[lane + q * 64]; v[q] = f; s += f; s2 += f * f; }
  #pragma unroll
  for (int off = 32; off; off >>= 1) { s += __shfl_xor(s, off); s2 += __shfl_xor(s2, off); }
  float mean = s * (1.f / DIMC);
  float var  = s2 * (1.f / DIMC) - mean * mean;
  float rstd = rsqrtf(var + 1e-5f);
  #pragma unroll
  for (int q = 0; q < 6; q++) {
    int d = lane + q * 64;
    o[d] = f2bf((v[q] - mean) * rstd * w[d] + b[d]);
  }
}

// ---------- LN2 ----------
__global__ __launch_bounds__(64) void ln2_kernel(const float* __restrict__ x2,
    const float* __restrict__ w, const float* __restrict__ b, unsigned short* __restrict__ h2) {
  int t = blockIdx.x; int lane = threadIdx.x;
  const float* xr = x2 + (size_t)t * DIMC;
  unsigned short* o = h2 + (size_t)t * DIMC;
  float v[6]; float s = 0.f, s2 = 0.f;
  #pragma unroll
  for (int q = 0; q < 6; q++) { float f = xr[lane + q * 64]; v[q] = f; s += f; s2 += f * f; }
  #pragma unroll
  for (int off = 32; off; off >>= 1) { s += __shfl_xor(s, off); s2 += __shfl_xor(s2, off); }
  float mean = s * (1.f / DIMC);
  float var  = s2 * (1.f / DIMC) - mean * mean;
  float rstd = rsqrtf(var + 1e-5f);
  #pragma unroll
  for (int q = 0; q < 6; q++) {
    int d = lane + q * 64;
    o[d] = f2bf((v[q] - mean) * rstd * w[d] + b[d]);
  }
}

// ---------- bf16 MFMA GEMM: 3-buffer counted-vmcnt pipeline, swizzled LDS, XCD remap ----------
// Per wave per K-tile: 4 global_load_lds. Top-of-tile: s_waitcnt vmcnt(4) (own tile-t loads
// done, tile-t+1's 4 stay in flight) -> s_barrier (all waves' loads visible) -> stage t+2.
template <int EPI>
__global__ __launch_bounds__(256) void gemm_kernel(
    const unsigned short* __restrict__ A, const unsigned short* __restrict__ WT,
    int Mrows, int Kd,
    const float* __restrict__ bias, const float* __restrict__ addin,
    float* __restrict__ outf, unsigned short* __restrict__ outb,
    unsigned short* __restrict__ outb2) {
  __shared__ unsigned short As[3][128 * 32];
  __shared__ unsigned short Bs[3][128 * 32];
  // XCD-aware bijective remap (m204)
  const int nwg = gridDim.x * gridDim.y;
  const int flat = blockIdx.y * gridDim.x + blockIdx.x;
  const int xcd = flat & 7, q_ = nwg >> 3, r_ = nwg & 7;
  const int wg = (xcd < r_ ? xcd * (q_ + 1) : r_ * (q_ + 1) + (xcd - r_) * q_) + (flat >> 3);
  const int bx = wg / gridDim.y, by = wg - bx * gridDim.y;
  const int row0 = bx * 128, col0 = by * 128;
  const int tid = threadIdx.x;
  const int l = tid & 63, wid = tid >> 6;
  const int fr = l & 15, fk = (l >> 4) * 8;
  const int wr = (wid >> 1) * 64, wc = (wid & 1) * 64;
  const int sr = l >> 2, sc = (l & 3) * 8;
  const int scs = sc ^ (((sr >> 1) & 3) << 3);   // source col swizzle (shorts)
  const int rsw = ((fr >> 1) & 3) << 3;          // read col swizzle
  f32x4 acc[4][4] = {};
  const unsigned short* ap = A + (size_t)row0 * Kd;
  const unsigned short* bp = WT + (size_t)col0 * Kd;
  const int nt = Kd >> 5;

  auto stage = [&](int t, int b) {
    const int k0 = t * 32;
    #pragma unroll
    for (int j = 0; j < 2; j++) {
      int chunk = j * 4 + wid;
      gload16(ap + (size_t)(chunk * 16 + sr) * Kd + k0 + scs, &As[b][chunk * 512]);
      gload16(bp + (size_t)(chunk * 16 + sr) * Kd + k0 + scs, &Bs[b][chunk * 512]);
    }
  };
  stage(0, 0);
  stage(1, 1);
  int c = 0;
  for (int t = 0; t < nt; ++t) {
    if (t < nt - 1) asm volatile("s_waitcnt vmcnt(4)" ::: "memory");
    else            asm volatile("s_waitcnt vmcnt(0)" ::: "memory");
    __builtin_amdgcn_s_barrier();
    __builtin_amdgcn_sched_barrier(0);
    if (t + 2 < nt) stage(t + 2, (c + 2 >= 3) ? c - 1 : c + 2);
    short8 a[4], b[4];
    #pragma unroll
    for (int fi = 0; fi < 4; fi++) {
      a[fi] = *(const short8*)&As[c][(wr + fi * 16 + fr) * 32 + (fk ^ rsw)];
      b[fi] = *(const short8*)&Bs[c][(wc + fi * 16 + fr) * 32 + (fk ^ rsw)];
    }
    asm volatile("s_waitcnt lgkmcnt(0)" ::: "memory");
    __builtin_amdgcn_sched_barrier(0);
    __builtin_amdgcn_s_setprio(1);
    #pragma unroll
    for (int fi = 0; fi < 4; fi++)
      #pragma unroll
      for (int fj = 0; fj < 4; fj++)
        acc[fi][fj] = __builtin_amdgcn_mfma_f32_16x16x32_bf16(b[fj], a[fi], acc[fi][fj], 0, 0, 0);
    __builtin_amdgcn_s_setprio(0);
    c = (c + 1 >= 3) ? 0 : c + 1;
  }
  #pragma unroll
  for (int fi = 0; fi < 4; fi++) {
    const int gr = row0 + wr + fi * 16 + fr;
    if (gr >= Mrows) continue;
    int wv_ = 0, p = 0, valid = 1; size_t pixbase = 0;
    if (EPI == 0 || EPI == 1) { wv_ = gr / NTOK; p = gr - wv_ * NTOK; }
    if (EPI == 1) {
      int bb = wv_ / 25, rem2 = wv_ - bb * 25;
      int wi = rem2 / 5, wj = rem2 - wi * 5;
      int i = p / WSZ, j = p - i * WSZ;
      int rr = wi * WSZ + i, cc = wj * WSZ + j;
      valid = (rr < 64) && (cc < 64);
      pixbase = (((size_t)bb * 64 + rr) * 64 + cc) * DIMC;
    }
    #pragma unroll
    for (int fj = 0; fj < 4; fj++) {
      const int gcb = col0 + wc + fj * 16 + (l >> 4) * 4;
      f32x4 v = acc[fi][fj];
      float4 bv = *(const float4*)&bias[gcb];
      float t0 = v[0] + bv.x, t1 = v[1] + bv.y, t2 = v[2] + bv.z, t3 = v[3] + bv.w;
      if (EPI == 0) {
        int s = gcb / 384, rem = gcb - s * 384;
        int hh = rem >> 6, d0 = gcb & 63;
        int whh = wv_ * NHD + hh;
        if (s == 0) { t0 *= 0.125f; t1 *= 0.125f; t2 *= 0.125f; t3 *= 0.125f; }
        if (s < 2) {
          *(int2*)&outb[((size_t)s * NWH + whh) * (NTOK * 64) + p * 64 + d0] =
              make_int2((int)pkbf(t0, t1), (int)pkbf(t2, t3));
        } else {
          unsigned short* vb = outb2 + ((size_t)whh * 64 + d0) * 208 + p;
          vb[0] = f2bf(t0); vb[208] = f2bf(t1); vb[416] = f2bf(t2); vb[624] = f2bf(t3);
        }
      } else if (EPI == 1) {
        if (valid) {
          size_t idx = pixbase + gcb;
          float4 ad = *(const float4*)&addin[idx];
          *(float4*)&outf[idx] = make_float4(t0 + ad.x, t1 + ad.y, t2 + ad.z, t3 + ad.w);
        }
      } else if (EPI == 2) {
        *(int2*)&outb[(size_t)gr * MLPD + gcb] =
            make_int2((int)pkbf(gelu_t(t0), gelu_t(t1)), (int)pkbf(gelu_t(t2), gelu_t(t3)));
      } else {
        size_t idx = (size_t)gr * DIMC + gcb;
        float4 ad = *(const float4*)&addin[idx];
        *(float4*)&outf[idx] = make_float4(t0 + ad.x, t1 + ad.y, t2 + ad.z, t3 + ad.w);
      }
    }
  }
}

// ---------- 32x32 MFMA attention: in-register P, defer-max online softmax ----------
template <bool TAIL>
__device__ __forceinline__ void attn_chunk(
    int kk, int l31, int hi,
    const unsigned short* __restrict__ kg,
    const unsigned short* __restrict__ VT,
    const short8* qf, const short8* qrel,
    f32x16& olo, f32x16& ohi_, float& m_reg, float& s_run) {
  int key = kk * 32 + l31;
  int keyc = (TAIL && key > 195) ? 195 : key;
  f32x16 S = {};
  __builtin_amdgcn_s_setprio(1);
  #pragma unroll
  for (int m = 0; m < 4; m++) {
    short8 kf = *(const short8*)(kg + (size_t)keyc * 64 + m * 16 + hi * 8);
    S = __builtin_amdgcn_mfma_f32_32x32x16_bf16(kf, qf[m], S, 0, 0, 0);
  }
  {
    int ki = keyc / 14, kj = keyc - ki * 14;
    #pragma unroll
    for (int m2 = 0; m2 < 2; m2++) {
      short8 kh;
      #pragma unroll
      for (int j = 0; j < 8; j++) {
        int cc = m2 * 16 + hi * 8 + j;
        kh[j] = (short)((cc == ki || cc == 14 + kj) ? 0x3F80 : 0);
      }
      S = __builtin_amdgcn_mfma_f32_32x32x16_bf16(kh, qrel[m2], S, 0, 0, 0);
    }
  }
  __builtin_amdgcn_s_setprio(0);
  float pmax = -3e38f;
  #pragma unroll
  for (int r = 0; r < 16; r++) {
    if (TAIL) {
      int krow = kk * 32 + (r & 3) + 8 * (r >> 2) + 4 * hi;
      if (krow >= 196) S[r] = -3e38f;
    }
    pmax = fmaxf(pmax, S[r]);
  }
  pmax = fmaxf(pmax, __shfl_xor(pmax, 32));
  if (__any(pmax > m_reg + 8.f)) {
    float m_new = fmaxf(m_reg, pmax);
    float fac = __expf(m_reg - m_new);
    m_reg = m_new;
    s_run *= fac;
    #pragma unroll
    for (int r = 0; r < 16; r++) {
      int qr = (r & 3) + 8 * (r >> 2) + 4 * hi;
      float fr_ = __shfl(fac, qr);
      olo[r] *= fr_; ohi_[r] *= fr_;
    }
  }
  float psum = 0.f;
  #pragma unroll
  for (int r = 0; r < 16; r++) { S[r] = __expf(S[r] - m_reg); psum += S[r]; }
  s_run += psum;
  unsigned int pk[8];
  #pragma unroll
  for (int t = 0; t < 8; t++) pk[t] = pkbf(S[2 * t], S[2 * t + 1]);
  #pragma unroll
  for (int m2 = 0; m2 < 2; m2++) {
    int b_ = m2 * 4;
    unsigned int x0 = (unsigned int)__shfl_xor((int)pk[b_ + 0], 32);
    unsigned int x1 = (unsigned int)__shfl_xor((int)pk[b_ + 1], 32);
    unsigned int x2 = (unsigned int)__shfl_xor((int)pk[b_ + 2], 32);
    unsigned int x3 = (unsigned int)__shfl_xor((int)pk[b_ + 3], 32);
    unsigned int au[4];
    au[0] = hi ? x2 : pk[b_ + 0];
    au[1] = hi ? x3 : pk[b_ + 1];
    au[2] = hi ? pk[b_ + 2] : x0;
    au[3] = hi ? pk[b_ + 3] : x1;
    short8 pa; __builtin_memcpy(&pa, au, 16);
    int kb = kk * 32 + m2 * 16 + hi * 8;
    if (TAIL && kb > 208) kb = 208;
    short8 vblo = *(const short8*)&VT[l31 * 216 + kb];
    short8 vbhi = *(const short8*)&VT[(32 + l31) * 216 + kb];
    __builtin_amdgcn_s_setprio(1);
    olo  = __builtin_amdgcn_mfma_f32_32x32x16_bf16(pa, vblo, olo, 0, 0, 0);
    ohi_ = __builtin_amdgcn_mfma_f32_32x32x16_bf16(pa, vbhi, ohi_, 0, 0, 0);
    __builtin_amdgcn_s_setprio(0);
  }
}

__global__ __launch_bounds__(256) void attn32_kernel(
    const unsigned short* __restrict__ qk_g,
    const unsigned short* __restrict__ vT_g,
    const unsigned short* __restrict__ relcat,
    unsigned short* __restrict__ attnout) {
  __shared__ __align__(16) unsigned short VT[64 * 216];
  __shared__ __align__(16) unsigned short RELB[4][2048];
  const int wh = blockIdx.x;
  const int w = wh / NHD, h = wh - w * NHD;
  const int tid = threadIdx.x;
  const unsigned short* vrow = vT_g + (size_t)wh * 64 * 208;
  for (int e = tid; e < 64 * 27; e += 256) {
    int d = e / 27, c = e - d * 27;
    int4 val = {0, 0, 0, 0};
    if (c < 26) val = *(const int4*)(vrow + d * 208 + c * 8);
    *(int4*)&VT[d * 216 + c * 8] = val;
  }
  __syncthreads();
  const int l = tid & 63, wv = tid >> 6;
  const int l31 = l & 31, hi = l >> 5;
  unsigned short* RB = &RELB[wv][0];
  const unsigned short* qg = qk_g + (size_t)wh * (NTOK * 64);
  const unsigned short* kg = qk_g + (size_t)(NWH + wh) * (NTOK * 64);

  for (int tile = wv; tile < 7; tile += 4) {
    const int q0 = tile * 32;
    int qrow = q0 + l31; if (qrow > 195) qrow = 195;
    short8 qf[4];
    #pragma unroll
    for (int m = 0; m < 4; m++)
      qf[m] = *(const short8*)(qg + (size_t)qrow * 64 + m * 16 + hi * 8);
    #pragma unroll
    for (int rt = 0; rt < 2; rt++) {
      f32x16 cr = {};
      __builtin_amdgcn_s_setprio(1);
      #pragma unroll
      for (int m = 0; m < 4; m++) {
        short8 af = *(const short8*)(relcat + (rt * 32 + l31) * 64 + m * 16 + hi * 8);
        cr = __builtin_amdgcn_mfma_f32_32x32x16_bf16(af, qf[m], cr, 0, 0, 0);
      }
      __builtin_amdgcn_s_setprio(0);
      #pragma unroll
      for (int t = 0; t < 8; t++) {
        int rr = rt * 32 + ((2 * t) & 3) + 8 * (t >> 1) + 4 * hi;
        *(unsigned int*)&RB[l31 * 64 + rr] = pkbf(cr[2 * t], cr[2 * t + 1]);
      }
    }
    __builtin_amdgcn_wave_barrier();
    int qi = qrow / 14, qj = qrow - qi * 14;
    short8 qrel[2];
    #pragma unroll
    for (int m2 = 0; m2 < 2; m2++)
      #pragma unroll
      for (int j = 0; j < 8; j++) {
        int cc = m2 * 16 + hi * 8 + j;
        unsigned short vv = 0;
        if (cc < 14) vv = RB[l31 * 64 + (qi - cc + 13)];
        else if (cc < 28) vv = RB[l31 * 64 + 27 + (qj - (cc - 14) + 13)];
        qrel[m2][j] = (short)vv;
      }
    __builtin_amdgcn_wave_barrier();
    f32x16 olo = {}, ohi_ = {};
    float m_reg = -3e38f, s_run = 0.f;
    for (int kk = 0; kk < 6; kk++)
      attn_chunk<false>(kk, l31, hi, kg, VT, qf, qrel, olo, ohi_, m_reg, s_run);
    attn_chunk<true>(6, l31, hi, kg, VT, qf, qrel, olo, ohi_, m_reg, s_run);
    s_run += __shfl_xor(s_run, 32);
    float inv = 1.f / s_run;
    #pragma unroll
    for (int r = 0; r < 16; r++) {
      int qr = (r & 3) + 8 * (r >> 2) + 4 * hi;
      float ir = __shfl(inv, qr);
      int tok = q0 + qr;
      if (tok < 196) {
        size_t base = ((size_t)w * NTOK + tok) * DIMC + h * 64;
        attnout[base + l31] = f2bf(olo[r] * ir);
        attnout[base + 32 + l31] = f2bf(ohi_[r] * ir);
      }
    }
  }
}

extern "C" void kernel_launch(void* const* d_in, const int* in_sizes, int n_in,
                              void* d_out, int out_size, void* d_ws, size_t ws_size,
                              hipStream_t stream) {
  const float* x     = (const float*)d_in[0];
  const float* ln1w  = (const float*)d_in[1];
  const float* ln1b  = (const float*)d_in[2];
  const float* qkvw  = (const float*)d_in[3];
  const float* qkvb  = (const float*)d_in[4];
  const float* projw = (const float*)d_in[5];
  const float* projb = (const float*)d_in[6];
  const float* relh  = (const float*)d_in[7];
  const float* relw  = (const float*)d_in[8];
  const float* ln2w  = (const float*)d_in[9];
  const float* ln2b  = (const float*)d_in[10];
  const float* fc1w  = (const float*)d_in[11];
  const float* fc1b  = (const float*)d_in[12];
  const float* fc2w  = (const float*)d_in[13];
  const float* fc2b  = (const float*)d_in[14];

  const size_t R0 = 0;
  const size_t R1 = R0 + 50331648;
  const size_t R2 = R1 + 100663296;
  const size_t R3 = R2 + 30105600;
  const size_t NEED = R3 + 3547136;
  if (ws_size < NEED) return;
  char* ws = (char*)d_ws;
  unsigned short* xw     = (unsigned short*)(ws + R0);
  float*          x2     = (float*)(ws + R0);
  unsigned short* qk_g   = (unsigned short*)(ws + R1);
  unsigned short* vT_g   = qk_g + (size_t)2 * NWH * NTOK * 64;
  unsigned short* hidden = (unsigned short*)(ws + R1);
  unsigned short* attno  = (unsigned short*)(ws + R2);
  unsigned short* h2     = (unsigned short*)(ws + R2);
  unsigned short* qkvwT  = (unsigned short*)(ws + R3);
  unsigned short* projwT = qkvwT + 442368;
  unsigned short* fc1wT  = projwT + 147456;
  unsigned short* fc2wT  = fc1wT + 589824;
  unsigned short* relcat = fc2wT + 589824;

  wtrans_kernel<<<1728, 256, 0, stream>>>(qkvw, qkvwT, 384, 1152);
  wtrans_kernel<<<576, 256, 0, stream>>>(projw, projwT, 384, 384);
  wtrans_kernel<<<2304, 256, 0, stream>>>(fc1w, fc1wT, 384, 1536);
  wtrans_kernel<<<2304, 256, 0, stream>>>(fc2w, fc2wT, 1536, 384);
  relprep_kernel<<<16, 256, 0, stream>>>(relh, relw, relcat);
  vpad_kernel<<<900, 256, 0, stream>>>(vT_g);
  ln1win_kernel<<<MWIN, 64, 0, stream>>>(x, ln1w, ln1b, xw);
  gemm_kernel<0><<<dim3(307, 9), 256, 0, stream>>>(xw, qkvwT, MWIN, 384, qkvb, nullptr, nullptr, qk_g, vT_g);
  attn32_kernel<<<NWH, 256, 0, stream>>>(qk_g, vT_g, relcat, attno);
  gemm_kernel<1><<<dim3(307, 3), 256, 0, stream>>>(attno, projwT, MWIN, 384, projb, x, x2, nullptr, nullptr);
  ln2_kernel<<<MX, 64, 0, stream>>>(x2, ln2w, ln2b, h2);
  gemm_kernel<2><<<dim3(256, 12), 256, 0, stream>>>(h2, fc1wT, MX, 384, fc1b, nullptr, nullptr, hidden, nullptr);
  gemm_kernel<3><<<dim3(256, 3), 256, 0, stream>>>(hidden, fc2wT, MX, 1536, fc2b, x2, (float*)d_out, nullptr, nullptr);
}